// Round 6
// baseline (566.233 us; speedup 1.0000x reference)
//
#include <hip/hip_runtime.h>

#define N_NODES 50000
#define N_EDGES 600000
#define HID 128
#define N_GRAPHS 512
#define BN_EPS 1e-5f

// ---------------------------------------------------------------------------
// CSR build
// ---------------------------------------------------------------------------
__global__ void deg_count_kernel(const int* __restrict__ dst, int* __restrict__ deg, int nE) {
    int e = blockIdx.x * blockDim.x + threadIdx.x;
    if (e < nE) atomicAdd(&deg[dst[e]], 1);
}

__global__ __launch_bounds__(256) void alloc_kernel(int* __restrict__ cursor,
                                                    int* __restrict__ row_beg,
                                                    float* __restrict__ inv_deg,
                                                    int* __restrict__ total, int n) {
    __shared__ int tmp[256];
    __shared__ int base;
    int i = blockIdx.x * 256 + threadIdx.x;
    int d = (i < n) ? cursor[i] : 0;
    tmp[threadIdx.x] = d;
    __syncthreads();
#pragma unroll
    for (int off = 1; off < 256; off <<= 1) {
        int v = (threadIdx.x >= off) ? tmp[threadIdx.x - off] : 0;
        __syncthreads();
        tmp[threadIdx.x] += v;
        __syncthreads();
    }
    if (threadIdx.x == 255) base = atomicAdd(total, tmp[255]);
    __syncthreads();
    if (i < n) {
        int b = base + tmp[threadIdx.x] - d;
        row_beg[i] = b;
        cursor[i] = b;
        inv_deg[i] = 1.0f / fmaxf((float)d, 1.0f);
    }
}

__global__ void csr_fill_kernel(const int* __restrict__ src, const int* __restrict__ dst,
                                int* __restrict__ cursor, int* __restrict__ csr_src, int nE) {
    int e = blockIdx.x * blockDim.x + threadIdx.x;
    if (e < nE) {
        int pos = atomicAdd(&cursor[dst[e]], 1);
        csr_src[pos] = src[e];
    }
}

// ---------------------------------------------------------------------------
// gather aggregation; AFF: apply y = relu(v*cs[col]+sh[col]) to gathered rows
// ---------------------------------------------------------------------------
template<bool AFF>
__global__ void csr_aggregate_kernel(const float* __restrict__ feat,
                                     const int* __restrict__ row_beg,
                                     const int* __restrict__ row_end,
                                     const int* __restrict__ csr_src,
                                     const float* __restrict__ cs,
                                     const float* __restrict__ sh,
                                     float* __restrict__ agg, int n) {
    int gid = blockIdx.x * blockDim.x + threadIdx.x;
    int node = gid >> 5;
    int lane = gid & 31;
    if (node >= n) return;
    int beg = row_beg[node];
    int end = row_end[node];
    float4 cs4 = make_float4(0.f,0.f,0.f,0.f), sh4 = cs4;
    if (AFF) {
        cs4 = *(const float4*)(cs + lane * 4);
        sh4 = *(const float4*)(sh + lane * 4);
    }
    float4 acc = make_float4(0.f, 0.f, 0.f, 0.f);
    int e = beg;
    for (; e + 1 < end; e += 2) {
        int s0 = csr_src[e];
        int s1 = csr_src[e + 1];
        float4 v0 = ((const float4*)(feat + (size_t)s0 * HID))[lane];
        float4 v1 = ((const float4*)(feat + (size_t)s1 * HID))[lane];
        if (AFF) {
            v0.x = fmaxf(v0.x * cs4.x + sh4.x, 0.f); v1.x = fmaxf(v1.x * cs4.x + sh4.x, 0.f);
            v0.y = fmaxf(v0.y * cs4.y + sh4.y, 0.f); v1.y = fmaxf(v1.y * cs4.y + sh4.y, 0.f);
            v0.z = fmaxf(v0.z * cs4.z + sh4.z, 0.f); v1.z = fmaxf(v1.z * cs4.z + sh4.z, 0.f);
            v0.w = fmaxf(v0.w * cs4.w + sh4.w, 0.f); v1.w = fmaxf(v1.w * cs4.w + sh4.w, 0.f);
        }
        acc.x += v0.x + v1.x;
        acc.y += v0.y + v1.y;
        acc.z += v0.z + v1.z;
        acc.w += v0.w + v1.w;
    }
    if (e < end) {
        int s0 = csr_src[e];
        float4 v0 = ((const float4*)(feat + (size_t)s0 * HID))[lane];
        if (AFF) {
            v0.x = fmaxf(v0.x * cs4.x + sh4.x, 0.f);
            v0.y = fmaxf(v0.y * cs4.y + sh4.y, 0.f);
            v0.z = fmaxf(v0.z * cs4.z + sh4.z, 0.f);
            v0.w = fmaxf(v0.w * cs4.w + sh4.w, 0.f);
        }
        acc.x += v0.x; acc.y += v0.y; acc.z += v0.z; acc.w += v0.w;
    }
    ((float4*)(agg + (size_t)node * HID))[lane] = acc;
}

// ---------------------------------------------------------------------------
// 64x128-tile GEMM, 256 threads, per-thread 8 rows x 4 cols (round-3 shape,
// measured conflict-free), plus register-prefetch software pipeline:
// chunk i+1's global loads are issued before computing chunk i, hiding the
// ~900-cycle HBM latency behind the 2048-cycle FMA block.
//
// MODE 0 (fused GIN):  T1 = relu((A1+A2) @ W1 + b1);  C = T1 @ W2 + b2
// MODE 2 (SAGE):       C = (A1*scale) @ W1 + act(A2) @ W2 + b1
//                      act(v) = AFFB ? relu(v*csB+shB) : v
// STATS: accumulate column sum/sumsq of C into stats[0:128]/[128:256]
// ---------------------------------------------------------------------------
template<int MODE, bool STATS, bool AFFB>
__global__ __launch_bounds__(256) void gemm_tile_kernel(
    const float* __restrict__ A1, const float* __restrict__ A2,
    const float* __restrict__ W1, const float* __restrict__ W2,
    const float* __restrict__ b1, const float* __restrict__ b2,
    const float* __restrict__ scale,
    const float* __restrict__ csB, const float* __restrict__ shB,
    float* __restrict__ stats, float* __restrict__ C, int M)
{
    __shared__ float As[64 * 33];
    __shared__ float Ws[32 * 128];

    const int t = threadIdx.x;
    const int colg = t & 31;   const int col0 = colg * 4;
    const int rowg = t >> 5;   const int row0r = rowg * 8;
    const int row0 = blockIdx.x * 64;

    // fixed per-thread staging coords
    const int r0  = t >> 3;          // A row for i=0 (0..31); i=1 adds 32
    const int c40 = t & 7;           // A float4-col (0..7)
    const int wr0 = t >> 5;          // W row for i (adds 8 per i)
    const int wc0 = t & 31;          // W float4-col

    float acc[8][4];
#pragma unroll
    for (int j = 0; j < 8; j++)
#pragma unroll
        for (int c = 0; c < 4; c++) acc[j][c] = 0.f;

    // prefetch registers
    float4 pa[2], pa2[2], pw[4], pcs[2], psh[2];
    float  ps[2];

    const int NCH = (MODE == 2) ? 8 : 4;

    auto load_chunk = [&](int ch) {
        const float* Ap, *Wp;
        int kc;
        if (MODE == 2) {
            Ap = (ch < 4) ? A1 : A2;
            Wp = (ch < 4) ? W1 : W2;
            kc = (ch & 3) * 32;
        } else {
            Ap = A1; Wp = W1; kc = ch * 32;
        }
#pragma unroll
        for (int i = 0; i < 2; i++) {
            int grow = row0 + r0 + i * 32;
            float4 z = make_float4(0.f, 0.f, 0.f, 0.f);
            pa[i] = (grow < M) ? *(const float4*)(Ap + (size_t)grow * 128 + kc + c40 * 4) : z;
            if (MODE == 0)
                pa2[i] = (grow < M) ? *(const float4*)(A2 + (size_t)grow * 128 + kc + c40 * 4) : z;
            if (MODE == 2) {
                if (ch < 4) ps[i] = (grow < M) ? scale[grow] : 0.f;
                else if (AFFB) {
                    pcs[i] = *(const float4*)(csB + kc + c40 * 4);
                    psh[i] = *(const float4*)(shB + kc + c40 * 4);
                }
            }
        }
#pragma unroll
        for (int i = 0; i < 4; i++) {
            int wr = wr0 + i * 8;
            pw[i] = ((const float4*)(Wp + (size_t)(kc + wr) * 128))[wc0];
        }
    };

    auto store_chunk = [&](int ch) {
#pragma unroll
        for (int i = 0; i < 2; i++) {
            float4 v = pa[i];
            if (MODE == 0) {
                v.x += pa2[i].x; v.y += pa2[i].y; v.z += pa2[i].z; v.w += pa2[i].w;
            } else if (ch < 4) {
                v.x *= ps[i]; v.y *= ps[i]; v.z *= ps[i]; v.w *= ps[i];
            } else if (AFFB) {
                v.x = fmaxf(v.x * pcs[i].x + psh[i].x, 0.f);
                v.y = fmaxf(v.y * pcs[i].y + psh[i].y, 0.f);
                v.z = fmaxf(v.z * pcs[i].z + psh[i].z, 0.f);
                v.w = fmaxf(v.w * pcs[i].w + psh[i].w, 0.f);
            }
            float* p = As + (r0 + i * 32) * 33 + c40 * 4;
            p[0] = v.x; p[1] = v.y; p[2] = v.z; p[3] = v.w;
        }
#pragma unroll
        for (int i = 0; i < 4; i++)
            ((float4*)Ws)[(wr0 + i * 8) * 32 + wc0] = pw[i];
    };

    auto compute = [&]() {
#pragma unroll 2
        for (int k = 0; k < 32; k++) {
            float4 w = *(const float4*)(Ws + k * 128 + col0);
#pragma unroll
            for (int j = 0; j < 8; j++) {
                float a = As[(row0r + j) * 33 + k];
                acc[j][0] += a * w.x;
                acc[j][1] += a * w.y;
                acc[j][2] += a * w.z;
                acc[j][3] += a * w.w;
            }
        }
    };

    // ---------------- pipelined main loop ----------------
    load_chunk(0);
    store_chunk(0);
    __syncthreads();
    for (int ch = 0; ch < NCH; ch++) {
        if (ch + 1 < NCH) load_chunk(ch + 1);
        compute();
        __syncthreads();
        if (ch + 1 < NCH) {
            store_chunk(ch + 1);
            __syncthreads();
        }
    }

    float out[8][4];

    if (MODE == 0) {
        // T1 = relu(acc + b1)
        float4 bs = *(const float4*)(b1 + col0);
#pragma unroll
        for (int j = 0; j < 8; j++) {
            acc[j][0] = fmaxf(acc[j][0] + bs.x, 0.f);
            acc[j][1] = fmaxf(acc[j][1] + bs.y, 0.f);
            acc[j][2] = fmaxf(acc[j][2] + bs.z, 0.f);
            acc[j][3] = fmaxf(acc[j][3] + bs.w, 0.f);
        }

        // phase 2: T1 @ W2, T1 chunks sourced from registers, W2 prefetched
        float acc2[8][4];
#pragma unroll
        for (int j = 0; j < 8; j++)
#pragma unroll
            for (int c = 0; c < 4; c++) acc2[j][c] = 0.f;

        auto loadW2 = [&](int p) {
#pragma unroll
            for (int i = 0; i < 4; i++) {
                int wr = wr0 + i * 8;
                pw[i] = ((const float4*)(W2 + (size_t)(p * 32 + wr) * 128))[wc0];
            }
        };
        auto storeT1W = [&](int p) {
            if ((colg >> 3) == p) {
                int lc = (colg & 7) * 4;
#pragma unroll
                for (int j = 0; j < 8; j++) {
                    float* q = As + (row0r + j) * 33 + lc;
#pragma unroll
                    for (int c = 0; c < 4; c++) q[c] = acc[j][c];
                }
            }
#pragma unroll
            for (int i = 0; i < 4; i++)
                ((float4*)Ws)[(wr0 + i * 8) * 32 + wc0] = pw[i];
        };
        auto compute2 = [&]() {
#pragma unroll 2
            for (int k = 0; k < 32; k++) {
                float4 w = *(const float4*)(Ws + k * 128 + col0);
#pragma unroll
                for (int j = 0; j < 8; j++) {
                    float a = As[(row0r + j) * 33 + k];
                    acc2[j][0] += a * w.x;
                    acc2[j][1] += a * w.y;
                    acc2[j][2] += a * w.z;
                    acc2[j][3] += a * w.w;
                }
            }
        };

        loadW2(0);
        __syncthreads();   // phase-1 LDS reads done everywhere
        storeT1W(0);
        __syncthreads();
        for (int p = 0; p < 4; p++) {
            if (p + 1 < 4) loadW2(p + 1);
            compute2();
            __syncthreads();
            if (p + 1 < 4) {
                storeT1W(p + 1);
                __syncthreads();
            }
        }
        float4 c0 = *(const float4*)(b2 + col0);
#pragma unroll
        for (int j = 0; j < 8; j++) {
            out[j][0] = acc2[j][0] + c0.x;
            out[j][1] = acc2[j][1] + c0.y;
            out[j][2] = acc2[j][2] + c0.z;
            out[j][3] = acc2[j][3] + c0.w;
        }
    } else {
        float4 c0 = *(const float4*)(b1 + col0);
#pragma unroll
        for (int j = 0; j < 8; j++) {
            out[j][0] = acc[j][0] + c0.x;
            out[j][1] = acc[j][1] + c0.y;
            out[j][2] = acc[j][2] + c0.z;
            out[j][3] = acc[j][3] + c0.w;
        }
    }

    // =================== store + stats ===================
    float psum[4] = {0,0,0,0};
    float psq[4]  = {0,0,0,0};
#pragma unroll
    for (int j = 0; j < 8; j++) {
        int grow = row0 + row0r + j;
        if (grow >= M) continue;
        if (STATS) {
#pragma unroll
            for (int c = 0; c < 4; c++) { psum[c] += out[j][c]; psq[c] += out[j][c] * out[j][c]; }
        }
        *(float4*)(C + (size_t)grow * 128 + col0) = make_float4(out[j][0], out[j][1], out[j][2], out[j][3]);
    }

    if (STATS) {
        float* red = As;  // 8 x 129 padded
        __syncthreads();
#pragma unroll
        for (int c = 0; c < 4; c++) red[rowg * 129 + col0 + c] = psum[c];
        __syncthreads();
        if (t < 128) {
            float s = 0.f;
#pragma unroll
            for (int r = 0; r < 8; r++) s += red[r * 129 + t];
            atomicAdd(&stats[t], s);
        }
        __syncthreads();
#pragma unroll
        for (int c = 0; c < 4; c++) red[rowg * 129 + col0 + c] = psq[c];
        __syncthreads();
        if (t < 128) {
            float s = 0.f;
#pragma unroll
            for (int r = 0; r < 8; r++) s += red[r * 129 + t];
            atomicAdd(&stats[128 + t], s);
        }
    }
}

// ---------------------------------------------------------------------------
// BN finalize
// ---------------------------------------------------------------------------
__global__ void bn_finalize_kernel(const float* __restrict__ stats,
                                   const float* __restrict__ gamma,
                                   const float* __restrict__ beta,
                                   float* __restrict__ cs, float* __restrict__ sh) {
    int t = threadIdx.x;
    if (t >= 128) return;
    float inv_n = 1.0f / (float)N_NODES;
    float mu = stats[t] * inv_n;
    float var = stats[128 + t] * inv_n - mu * mu;
    float rs = rsqrtf(var + BN_EPS);
    float c = gamma[t] * rs;
    cs[t] = c;
    sh[t] = beta[t] - mu * c;
}

// ---------------------------------------------------------------------------
// global mean pool (fused BN affine + relu)
// ---------------------------------------------------------------------------
__global__ void gstart_kernel(const int* __restrict__ batch, int* __restrict__ gstart, int n) {
    int g = blockIdx.x * blockDim.x + threadIdx.x;
    if (g > N_GRAPHS) return;
    int lo = 0, hi = n;
    while (lo < hi) {
        int mid = (lo + hi) >> 1;
        if (batch[mid] < g) lo = mid + 1; else hi = mid;
    }
    gstart[g] = lo;
}

__global__ __launch_bounds__(128) void pool_mean_kernel(const float* __restrict__ h,
                                                        const int* __restrict__ gstart,
                                                        const float* __restrict__ cs,
                                                        const float* __restrict__ sh,
                                                        float* __restrict__ out) {
    int g = blockIdx.x;
    int col = threadIdx.x;
    int beg = gstart[g];
    int end = gstart[g + 1];
    float c = cs[col], b = sh[col];
    float s = 0.f;
    for (int i = beg; i < end; i++)
        s += fmaxf(h[(size_t)i * 128 + col] * c + b, 0.f);
    float cnt = fmaxf((float)(end - beg), 1.0f);
    out[(size_t)g * 128 + col] = s / cnt;
}

// ---------------------------------------------------------------------------
extern "C" void kernel_launch(void* const* d_in, const int* in_sizes, int n_in,
                              void* d_out, int out_size, void* d_ws, size_t ws_size,
                              hipStream_t stream) {
    const float* x    = (const float*)d_in[0];
    const int*   ei   = (const int*)d_in[1];
    const int*   src  = ei;
    const int*   dst  = ei + N_EDGES;
    const int*   batch = (const int*)d_in[2];
    const float* gw1  = (const float*)d_in[3];
    const float* gb1  = (const float*)d_in[4];
    const float* gw2  = (const float*)d_in[5];
    const float* gb2  = (const float*)d_in[6];
    const float* swl  = (const float*)d_in[7];
    const float* sbl  = (const float*)d_in[8];
    const float* swr  = (const float*)d_in[9];
    const float* bng  = (const float*)d_in[10];
    const float* bnb  = (const float*)d_in[11];
    float* out = (float*)d_out;

    float* ws      = (float*)d_ws;
    float* hA      = ws;                      // 6.4M
    float* hB      = ws + 6400000;            // 6.4M
    float* agg     = ws + 12800000;           // 6.4M
    float* inv_deg = ws + 19200000;           // 50000
    float* stats   = ws + 19250000;           // 3 x 256
    float* cs      = ws + 19250768;           // 3 x 128
    float* sh      = ws + 19251152;           // 3 x 128
    int*   row_beg = (int*)(ws + 19251536);   // 50000
    int*   cursor  = (int*)(ws + 19301536);   // 50000
    int*   csr_src = (int*)(ws + 19351536);   // 600000
    int*   gstart  = (int*)(ws + 19951536);   // 513
    int*   total   = (int*)(ws + 19952049);   // 1

    const int gemm_blocks = (N_NODES + 63) / 64;          // 782
    const int aggr_blocks = (N_NODES * 32 + 255) / 256;

    // ---- CSR build ----
    hipMemsetAsync(cursor, 0, N_NODES * sizeof(int), stream);
    hipMemsetAsync(total, 0, sizeof(int), stream);
    hipMemsetAsync(stats, 0, 3 * 256 * sizeof(float), stream);
    deg_count_kernel<<<(N_EDGES + 255) / 256, 256, 0, stream>>>(dst, cursor, N_EDGES);
    alloc_kernel<<<(N_NODES + 255) / 256, 256, 0, stream>>>(cursor, row_beg, inv_deg, total, N_NODES);
    csr_fill_kernel<<<(N_EDGES + 255) / 256, 256, 0, stream>>>(src, dst, cursor, csr_src, N_EDGES);
    gstart_kernel<<<3, 256, 0, stream>>>(batch, gstart, N_NODES);

    // ---- GIN (fused two GEMMs) ----
    csr_aggregate_kernel<false><<<aggr_blocks, 256, 0, stream>>>(
        x, row_beg, cursor, csr_src, nullptr, nullptr, agg, N_NODES);
    gemm_tile_kernel<0, true, false><<<gemm_blocks, 256, 0, stream>>>(
        x, agg, gw1, gw2, gb1, gb2, nullptr, nullptr, nullptr, stats + 0, hB, N_NODES);
    bn_finalize_kernel<<<1, 128, 0, stream>>>(stats + 0, bng + 0 * HID, bnb + 0 * HID, cs + 0, sh + 0);

    // ---- SAGE 0 ----
    csr_aggregate_kernel<true><<<aggr_blocks, 256, 0, stream>>>(
        hB, row_beg, cursor, csr_src, cs + 0, sh + 0, agg, N_NODES);
    gemm_tile_kernel<2, true, true><<<gemm_blocks, 256, 0, stream>>>(
        agg, hB, swl + 0 * HID * HID, swr + 0 * HID * HID, sbl + 0 * HID, nullptr,
        inv_deg, cs + 0, sh + 0, stats + 256, hA, N_NODES);
    bn_finalize_kernel<<<1, 128, 0, stream>>>(stats + 256, bng + 1 * HID, bnb + 1 * HID, cs + 128, sh + 128);

    // ---- SAGE 1 ----
    csr_aggregate_kernel<true><<<aggr_blocks, 256, 0, stream>>>(
        hA, row_beg, cursor, csr_src, cs + 128, sh + 128, agg, N_NODES);
    gemm_tile_kernel<2, true, true><<<gemm_blocks, 256, 0, stream>>>(
        agg, hA, swl + 1 * HID * HID, swr + 1 * HID * HID, sbl + 1 * HID, nullptr,
        inv_deg, cs + 128, sh + 128, stats + 512, hB, N_NODES);
    bn_finalize_kernel<<<1, 128, 0, stream>>>(stats + 512, bng + 2 * HID, bnb + 2 * HID, cs + 256, sh + 256);

    // ---- pool ----
    pool_mean_kernel<<<N_GRAPHS, 128, 0, stream>>>(hB, gstart, cs + 256, sh + 256, out);
}

// Round 7
// 476.723 us; speedup vs baseline: 1.1878x; 1.1878x over previous
//
#include <hip/hip_runtime.h>

#define N_NODES 50000
#define N_EDGES 600000
#define HID 128
#define N_GRAPHS 512
#define BN_EPS 1e-5f

typedef __attribute__((ext_vector_type(8))) short bf16x8;
typedef __attribute__((ext_vector_type(4))) float f32x4;

__device__ __forceinline__ unsigned short f2b(float f) {
    unsigned u = __float_as_uint(f);
    return (unsigned short)((u + 0x7FFFu + ((u >> 16) & 1u)) >> 16);
}
__device__ __forceinline__ float b2f(unsigned short h) {
    return __uint_as_float(((unsigned)h) << 16);
}

// ---------------------------------------------------------------------------
// CSR build
// ---------------------------------------------------------------------------
__global__ void deg_count_kernel(const int* __restrict__ dst, int* __restrict__ deg, int nE) {
    int e = blockIdx.x * blockDim.x + threadIdx.x;
    if (e < nE) atomicAdd(&deg[dst[e]], 1);
}

__global__ __launch_bounds__(256) void alloc_kernel(int* __restrict__ cursor,
                                                    int* __restrict__ row_beg,
                                                    float* __restrict__ inv_deg,
                                                    int* __restrict__ total, int n) {
    __shared__ int tmp[256];
    __shared__ int base;
    int i = blockIdx.x * 256 + threadIdx.x;
    int d = (i < n) ? cursor[i] : 0;
    tmp[threadIdx.x] = d;
    __syncthreads();
#pragma unroll
    for (int off = 1; off < 256; off <<= 1) {
        int v = (threadIdx.x >= off) ? tmp[threadIdx.x - off] : 0;
        __syncthreads();
        tmp[threadIdx.x] += v;
        __syncthreads();
    }
    if (threadIdx.x == 255) base = atomicAdd(total, tmp[255]);
    __syncthreads();
    if (i < n) {
        int b = base + tmp[threadIdx.x] - d;
        row_beg[i] = b;
        cursor[i] = b;
        inv_deg[i] = 1.0f / fmaxf((float)d, 1.0f);
    }
}

__global__ void csr_fill_kernel(const int* __restrict__ src, const int* __restrict__ dst,
                                int* __restrict__ cursor, int* __restrict__ csr_src, int nE) {
    int e = blockIdx.x * blockDim.x + threadIdx.x;
    if (e < nE) {
        int pos = atomicAdd(&cursor[dst[e]], 1);
        csr_src[pos] = src[e];
    }
}

// ---------------------------------------------------------------------------
// weight transpose + bf16 convert: wt[m][n][k] = bf16(W_m[k][n]), 6 matrices
// ---------------------------------------------------------------------------
__global__ void wconvert_kernel(const float* __restrict__ gw1, const float* __restrict__ gw2,
                                const float* __restrict__ swl, const float* __restrict__ swr,
                                unsigned short* __restrict__ wt) {
    int gid = blockIdx.x * 256 + threadIdx.x;   // 6*16384
    int m = gid >> 14;
    int e = gid & 16383;
    int k = e >> 7;
    int n = e & 127;
    const float* src = (m == 0) ? gw1 : (m == 1) ? gw2 : (m == 2) ? swl
                     : (m == 3) ? swr : (m == 4) ? (swl + 16384) : (swr + 16384);
    wt[m * 16384 + n * 128 + k] = f2b(src[k * 128 + n]);
}

// ---------------------------------------------------------------------------
// elementwise converts (one thread = 4 columns of one node)
// ---------------------------------------------------------------------------
__global__ void convert_x_kernel(const float* __restrict__ x, unsigned short* __restrict__ x16, int n) {
    int gid = blockIdx.x * blockDim.x + threadIdx.x;
    int i = gid >> 5, l = gid & 31;
    if (i >= n) return;
    int c0 = l * 4;
    float4 v = *(const float4*)(x + (size_t)i * 128 + c0);
    ushort4 o;
    o.x = f2b(v.x); o.y = f2b(v.y); o.z = f2b(v.z); o.w = f2b(v.w);
    *(ushort4*)(x16 + (size_t)i * 128 + c0) = o;
}

__global__ void convert_xa_kernel(const float* __restrict__ x, const unsigned short* __restrict__ agg16,
                                  unsigned short* __restrict__ xa16, int n) {
    int gid = blockIdx.x * blockDim.x + threadIdx.x;
    int i = gid >> 5, l = gid & 31;
    if (i >= n) return;
    int c0 = l * 4;
    float4 v = *(const float4*)(x + (size_t)i * 128 + c0);
    ushort4 a = *(const ushort4*)(agg16 + (size_t)i * 128 + c0);
    ushort4 o;
    o.x = f2b(v.x + b2f(a.x)); o.y = f2b(v.y + b2f(a.y));
    o.z = f2b(v.z + b2f(a.z)); o.w = f2b(v.w + b2f(a.w));
    *(ushort4*)(xa16 + (size_t)i * 128 + c0) = o;
}

__global__ void convert_h_kernel(const float* __restrict__ hpre, const float* __restrict__ cs,
                                 const float* __restrict__ sh, unsigned short* __restrict__ hb, int n) {
    int gid = blockIdx.x * blockDim.x + threadIdx.x;
    int i = gid >> 5, l = gid & 31;
    if (i >= n) return;
    int c0 = l * 4;
    float4 v = *(const float4*)(hpre + (size_t)i * 128 + c0);
    float4 c = *(const float4*)(cs + c0);
    float4 s = *(const float4*)(sh + c0);
    ushort4 o;
    o.x = f2b(fmaxf(v.x * c.x + s.x, 0.f));
    o.y = f2b(fmaxf(v.y * c.y + s.y, 0.f));
    o.z = f2b(fmaxf(v.z * c.z + s.z, 0.f));
    o.w = f2b(fmaxf(v.w * c.w + s.w, 0.f));
    *(ushort4*)(hb + (size_t)i * 128 + c0) = o;
}

// ---------------------------------------------------------------------------
// bf16 gather aggregation: agg[i] = (sum_{e} feat[src[e]]) * (MEAN ? inv_deg : 1)
// 32 lanes per node, 4 cols per lane (8B loads), fp32 accumulate, bf16 out
// ---------------------------------------------------------------------------
template<bool MEAN>
__global__ void csr_aggregate_bf16_kernel(const unsigned short* __restrict__ feat,
                                          const int* __restrict__ row_beg,
                                          const int* __restrict__ row_end,
                                          const int* __restrict__ csr_src,
                                          const float* __restrict__ inv_deg,
                                          unsigned short* __restrict__ agg, int n) {
    int gid = blockIdx.x * blockDim.x + threadIdx.x;
    int node = gid >> 5;
    int lane = gid & 31;
    if (node >= n) return;
    int beg = row_beg[node];
    int end = row_end[node];
    int c0 = lane * 4;
    float a0 = 0.f, a1 = 0.f, a2 = 0.f, a3 = 0.f;
    int e = beg;
    for (; e + 1 < end; e += 2) {
        int s0 = csr_src[e];
        int s1 = csr_src[e + 1];
        ushort4 v0 = *(const ushort4*)(feat + (size_t)s0 * 128 + c0);
        ushort4 v1 = *(const ushort4*)(feat + (size_t)s1 * 128 + c0);
        a0 += b2f(v0.x) + b2f(v1.x);
        a1 += b2f(v0.y) + b2f(v1.y);
        a2 += b2f(v0.z) + b2f(v1.z);
        a3 += b2f(v0.w) + b2f(v1.w);
    }
    if (e < end) {
        int s0 = csr_src[e];
        ushort4 v0 = *(const ushort4*)(feat + (size_t)s0 * 128 + c0);
        a0 += b2f(v0.x); a1 += b2f(v0.y); a2 += b2f(v0.z); a3 += b2f(v0.w);
    }
    if (MEAN) {
        float s = inv_deg[node];
        a0 *= s; a1 *= s; a2 *= s; a3 *= s;
    }
    ushort4 o;
    o.x = f2b(a0); o.y = f2b(a1); o.z = f2b(a2); o.w = f2b(a3);
    *(ushort4*)(agg + (size_t)node * 128 + c0) = o;
}

// ---------------------------------------------------------------------------
// MFMA GEMM: 64 rows/block, 4 waves, each wave = 16 rows x 128 cols (8 frags).
// A/B frags loaded directly from global bf16 (B = transposed weights, L1-hot).
// MODE 0 (GIN): C = relu(A1@W1 + b1) @ W2 + b2       (T1 via per-wave LDS)
// MODE 2 (SAGE): C = A1@W1 + A2@W2 + b1
// Always accumulates column sum/sumsq into stats[0:128]/[128:256].
// ---------------------------------------------------------------------------
template<int MODE>
__global__ __launch_bounds__(256) void gemm_mfma_kernel(
    const unsigned short* __restrict__ A1, const unsigned short* __restrict__ A2,
    const unsigned short* __restrict__ W1t, const unsigned short* __restrict__ W2t,
    const float* __restrict__ b1, const float* __restrict__ b2,
    float* __restrict__ stats, float* __restrict__ C, int M)
{
    __shared__ unsigned short t1[4][16][136];   // pad 136: 16B-aligned rows, conflict-free b128
    __shared__ float red[4][128];

    const int t = threadIdx.x;
    const int wave = t >> 6;
    const int lane = t & 63;
    const int m16 = lane & 15;
    const int quad = lane >> 4;
    const int k0 = quad * 8;
    const int row0 = blockIdx.x * 64 + wave * 16;
    const int arow = row0 + m16;
    const bool aok = arow < M;

    const bf16x8 zero8 = {0, 0, 0, 0, 0, 0, 0, 0};
    f32x4 acc[8];
#pragma unroll
    for (int i = 0; i < 8; i++) acc[i] = (f32x4){0.f, 0.f, 0.f, 0.f};

    // ---------------- phase 1: A1 @ W1 ----------------
#pragma unroll
    for (int kc = 0; kc < 128; kc += 32) {
        bf16x8 a1 = aok ? *(const bf16x8*)(A1 + (size_t)arow * 128 + kc + k0) : zero8;
        bf16x8 a2 = zero8;
        if (MODE == 2)
            a2 = aok ? *(const bf16x8*)(A2 + (size_t)arow * 128 + kc + k0) : zero8;
#pragma unroll
        for (int ct = 0; ct < 8; ct++) {
            bf16x8 w1 = *(const bf16x8*)(W1t + (size_t)(ct * 16 + m16) * 128 + kc + k0);
            acc[ct] = __builtin_amdgcn_mfma_f32_16x16x32_bf16(a1, w1, acc[ct], 0, 0, 0);
            if (MODE == 2) {
                bf16x8 w2 = *(const bf16x8*)(W2t + (size_t)(ct * 16 + m16) * 128 + kc + k0);
                acc[ct] = __builtin_amdgcn_mfma_f32_16x16x32_bf16(a2, w2, acc[ct], 0, 0, 0);
            }
        }
    }

    if (MODE == 0) {
        // T1 = relu(acc + b1) -> per-wave LDS strip (C-layout -> A-layout transform)
#pragma unroll
        for (int ct = 0; ct < 8; ct++) {
            float bias = b1[ct * 16 + m16];
#pragma unroll
            for (int r = 0; r < 4; r++) {
                float v = fmaxf(acc[ct][r] + bias, 0.f);
                t1[wave][quad * 4 + r][ct * 16 + m16] = f2b(v);
            }
        }
        __syncthreads();
#pragma unroll
        for (int i = 0; i < 8; i++) acc[i] = (f32x4){0.f, 0.f, 0.f, 0.f};
        // phase 2: T1 @ W2
#pragma unroll
        for (int kc = 0; kc < 128; kc += 32) {
            bf16x8 a = *(const bf16x8*)&t1[wave][m16][kc + k0];
#pragma unroll
            for (int ct = 0; ct < 8; ct++) {
                bf16x8 w2 = *(const bf16x8*)(W2t + (size_t)(ct * 16 + m16) * 128 + kc + k0);
                acc[ct] = __builtin_amdgcn_mfma_f32_16x16x32_bf16(a, w2, acc[ct], 0, 0, 0);
            }
        }
    }

    // ---------------- epilogue: bias, store, stats ----------------
    const float* bb = (MODE == 0) ? b2 : b1;
    float psum[8], psq[8];
#pragma unroll
    for (int ct = 0; ct < 8; ct++) { psum[ct] = 0.f; psq[ct] = 0.f; }

#pragma unroll
    for (int ct = 0; ct < 8; ct++) {
        int col = ct * 16 + m16;
        float bias = bb[col];
#pragma unroll
        for (int r = 0; r < 4; r++) {
            int orow = row0 + quad * 4 + r;
            if (orow < M) {
                float v = acc[ct][r] + bias;
                C[(size_t)orow * 128 + col] = v;
                psum[ct] += v;
                psq[ct] += v * v;
            }
        }
    }
    // reduce the 4 quads (same column set) within the wave
#pragma unroll
    for (int ct = 0; ct < 8; ct++) {
        psum[ct] += __shfl_down(psum[ct], 32, 64);
        psum[ct] += __shfl_down(psum[ct], 16, 64);
        psq[ct]  += __shfl_down(psq[ct], 32, 64);
        psq[ct]  += __shfl_down(psq[ct], 16, 64);
    }
    if (MODE == 0) __syncthreads();   // t1 strip reuse safety before red writes? (distinct arrays; barrier aligns phases)
    if (lane < 16) {
#pragma unroll
        for (int ct = 0; ct < 8; ct++) red[wave][ct * 16 + m16] = psum[ct];
    }
    __syncthreads();
    if (t < 128) {
        float s = red[0][t] + red[1][t] + red[2][t] + red[3][t];
        atomicAdd(&stats[t], s);
    }
    __syncthreads();
    if (lane < 16) {
#pragma unroll
        for (int ct = 0; ct < 8; ct++) red[wave][ct * 16 + m16] = psq[ct];
    }
    __syncthreads();
    if (t < 128) {
        float s = red[0][t] + red[1][t] + red[2][t] + red[3][t];
        atomicAdd(&stats[128 + t], s);
    }
}

// ---------------------------------------------------------------------------
// BN finalize
// ---------------------------------------------------------------------------
__global__ void bn_finalize_kernel(const float* __restrict__ stats,
                                   const float* __restrict__ gamma,
                                   const float* __restrict__ beta,
                                   float* __restrict__ cs, float* __restrict__ sh) {
    int t = threadIdx.x;
    if (t >= 128) return;
    float inv_n = 1.0f / (float)N_NODES;
    float mu = stats[t] * inv_n;
    float var = stats[128 + t] * inv_n - mu * mu;
    float rs = rsqrtf(var + BN_EPS);
    float c = gamma[t] * rs;
    cs[t] = c;
    sh[t] = beta[t] - mu * c;
}

// ---------------------------------------------------------------------------
// global mean pool over sorted batch ids, fused BN affine + relu
// ---------------------------------------------------------------------------
__global__ void gstart_kernel(const int* __restrict__ batch, int* __restrict__ gstart, int n) {
    int g = blockIdx.x * blockDim.x + threadIdx.x;
    if (g > N_GRAPHS) return;
    int lo = 0, hi = n;
    while (lo < hi) {
        int mid = (lo + hi) >> 1;
        if (batch[mid] < g) lo = mid + 1; else hi = mid;
    }
    gstart[g] = lo;
}

__global__ __launch_bounds__(128) void pool_mean_kernel(const float* __restrict__ h,
                                                        const int* __restrict__ gstart,
                                                        const float* __restrict__ cs,
                                                        const float* __restrict__ sh,
                                                        float* __restrict__ out) {
    int g = blockIdx.x;
    int col = threadIdx.x;
    int beg = gstart[g];
    int end = gstart[g + 1];
    float c = cs[col], b = sh[col];
    float s = 0.f;
    for (int i = beg; i < end; i++)
        s += fmaxf(h[(size_t)i * 128 + col] * c + b, 0.f);
    float cnt = fmaxf((float)(end - beg), 1.0f);
    out[(size_t)g * 128 + col] = s / cnt;
}

// ---------------------------------------------------------------------------
extern "C" void kernel_launch(void* const* d_in, const int* in_sizes, int n_in,
                              void* d_out, int out_size, void* d_ws, size_t ws_size,
                              hipStream_t stream) {
    const float* x    = (const float*)d_in[0];
    const int*   ei   = (const int*)d_in[1];
    const int*   src  = ei;
    const int*   dst  = ei + N_EDGES;
    const int*   batch = (const int*)d_in[2];
    const float* gw1  = (const float*)d_in[3];
    const float* gb1  = (const float*)d_in[4];
    const float* gw2  = (const float*)d_in[5];
    const float* gb2  = (const float*)d_in[6];
    const float* swl  = (const float*)d_in[7];
    const float* sbl  = (const float*)d_in[8];
    const float* swr  = (const float*)d_in[9];
    const float* bng  = (const float*)d_in[10];
    const float* bnb  = (const float*)d_in[11];
    float* out = (float*)d_out;

    // workspace (float units)
    float* ws = (float*)d_ws;
    float*          hpre   = ws;                              // 6.4M  fp32 pre-BN
    unsigned short* agg16  = (unsigned short*)(ws + 6400000); // 6.4M u16 -> 3.2M fl
    unsigned short* hx16   = (unsigned short*)(ws + 9600000); // xa16 then hb16
    unsigned short* x16    = (unsigned short*)(ws + 12800000);
    unsigned short* wt     = (unsigned short*)(ws + 16000000); // 6*16384 u16
    float*          inv_deg= ws + 16050000;                   // 50000
    float*          stats  = ws + 16100000;                   // 3*256
    float*          cs     = ws + 16100768;                   // 3*128
    float*          sh     = ws + 16101152;                   // 3*128
    int*            row_beg= (int*)(ws + 16101536);           // 50000
    int*            cursor = (int*)(ws + 16151536);           // 50000
    int*            csr_src= (int*)(ws + 16201536);           // 600000
    int*            gstart = (int*)(ws + 16801536);           // 513
    int*            total  = (int*)(ws + 16802049);           // 1

    const int gemm_blocks = (N_NODES + 63) / 64;              // 782
    const int elem_blocks = (N_NODES * 32 + 255) / 256;       // 6250

    // ---- CSR build ----
    hipMemsetAsync(cursor, 0, N_NODES * sizeof(int), stream);
    hipMemsetAsync(total, 0, sizeof(int), stream);
    hipMemsetAsync(stats, 0, 3 * 256 * sizeof(float), stream);
    deg_count_kernel<<<(N_EDGES + 255) / 256, 256, 0, stream>>>(dst, cursor, N_EDGES);
    alloc_kernel<<<(N_NODES + 255) / 256, 256, 0, stream>>>(cursor, row_beg, inv_deg, total, N_NODES);
    csr_fill_kernel<<<(N_EDGES + 255) / 256, 256, 0, stream>>>(src, dst, cursor, csr_src, N_EDGES);
    gstart_kernel<<<3, 256, 0, stream>>>(batch, gstart, N_NODES);

    // ---- weights -> bf16 transposed ----
    wconvert_kernel<<<(6 * 16384) / 256, 256, 0, stream>>>(gw1, gw2, swl, swr, wt);

    // ---- GIN ----
    convert_x_kernel<<<elem_blocks, 256, 0, stream>>>(x, x16, N_NODES);
    csr_aggregate_bf16_kernel<false><<<elem_blocks, 256, 0, stream>>>(
        x16, row_beg, cursor, csr_src, nullptr, agg16, N_NODES);
    convert_xa_kernel<<<elem_blocks, 256, 0, stream>>>(x, agg16, hx16, N_NODES);
    gemm_mfma_kernel<0><<<gemm_blocks, 256, 0, stream>>>(
        hx16, nullptr, wt + 0 * 16384, wt + 1 * 16384, gb1, gb2, stats + 0, hpre, N_NODES);
    bn_finalize_kernel<<<1, 128, 0, stream>>>(stats + 0, bng + 0 * HID, bnb + 0 * HID, cs + 0, sh + 0);

    // ---- SAGE 0 ----
    convert_h_kernel<<<elem_blocks, 256, 0, stream>>>(hpre, cs + 0, sh + 0, hx16, N_NODES);
    csr_aggregate_bf16_kernel<true><<<elem_blocks, 256, 0, stream>>>(
        hx16, row_beg, cursor, csr_src, inv_deg, agg16, N_NODES);
    gemm_mfma_kernel<2><<<gemm_blocks, 256, 0, stream>>>(
        agg16, hx16, wt + 2 * 16384, wt + 3 * 16384, sbl + 0 * HID, nullptr, stats + 256, hpre, N_NODES);
    bn_finalize_kernel<<<1, 128, 0, stream>>>(stats + 256, bng + 1 * HID, bnb + 1 * HID, cs + 128, sh + 128);

    // ---- SAGE 1 ----
    convert_h_kernel<<<elem_blocks, 256, 0, stream>>>(hpre, cs + 128, sh + 128, hx16, N_NODES);
    csr_aggregate_bf16_kernel<true><<<elem_blocks, 256, 0, stream>>>(
        hx16, row_beg, cursor, csr_src, inv_deg, agg16, N_NODES);
    gemm_mfma_kernel<2><<<gemm_blocks, 256, 0, stream>>>(
        agg16, hx16, wt + 4 * 16384, wt + 5 * 16384, sbl + 1 * HID, nullptr, stats + 512, hpre, N_NODES);
    bn_finalize_kernel<<<1, 128, 0, stream>>>(stats + 512, bng + 2 * HID, bnb + 2 * HID, cs + 256, sh + 256);

    // ---- pool ----
    pool_mean_kernel<<<N_GRAPHS, 128, 0, stream>>>(hpre, gstart, cs + 256, sh + 256, out);
}

// Round 8
// 456.346 us; speedup vs baseline: 1.2408x; 1.0447x over previous
//
#include <hip/hip_runtime.h>

#define N_NODES 50000
#define N_EDGES 600000
#define HID 128
#define N_GRAPHS 512
#define BN_EPS 1e-5f

typedef __attribute__((ext_vector_type(8))) short bf16x8;
typedef __attribute__((ext_vector_type(4))) float f32x4;

__device__ __forceinline__ unsigned short f2b(float f) {
    unsigned u = __float_as_uint(f);
    return (unsigned short)((u + 0x7FFFu + ((u >> 16) & 1u)) >> 16);
}
__device__ __forceinline__ float b2f(unsigned short h) {
    return __uint_as_float(((unsigned)h) << 16);
}

// ---------------------------------------------------------------------------
// CSR build
// ---------------------------------------------------------------------------
__global__ void deg_count_kernel(const int* __restrict__ dst, int* __restrict__ deg, int nE) {
    int e = blockIdx.x * blockDim.x + threadIdx.x;
    if (e < nE) atomicAdd(&deg[dst[e]], 1);
}

__global__ __launch_bounds__(256) void alloc_kernel(int* __restrict__ cursor,
                                                    int* __restrict__ row_beg,
                                                    float* __restrict__ inv_deg,
                                                    int* __restrict__ total, int n) {
    __shared__ int tmp[256];
    __shared__ int base;
    int i = blockIdx.x * 256 + threadIdx.x;
    int d = (i < n) ? cursor[i] : 0;
    tmp[threadIdx.x] = d;
    __syncthreads();
#pragma unroll
    for (int off = 1; off < 256; off <<= 1) {
        int v = (threadIdx.x >= off) ? tmp[threadIdx.x - off] : 0;
        __syncthreads();
        tmp[threadIdx.x] += v;
        __syncthreads();
    }
    if (threadIdx.x == 255) base = atomicAdd(total, tmp[255]);
    __syncthreads();
    if (i < n) {
        int b = base + tmp[threadIdx.x] - d;
        row_beg[i] = b;
        cursor[i] = b;
        inv_deg[i] = 1.0f / fmaxf((float)d, 1.0f);
    }
}

__global__ void csr_fill_kernel(const int* __restrict__ src, const int* __restrict__ dst,
                                int* __restrict__ cursor, int* __restrict__ csr_src, int nE) {
    int e = blockIdx.x * blockDim.x + threadIdx.x;
    if (e < nE) {
        int pos = atomicAdd(&cursor[dst[e]], 1);
        csr_src[pos] = src[e];
    }
}

// ---------------------------------------------------------------------------
// weight transpose + bf16 convert: wt[m][n][k] = bf16(W_m[k][n]), 6 matrices
// ---------------------------------------------------------------------------
__global__ void wconvert_kernel(const float* __restrict__ gw1, const float* __restrict__ gw2,
                                const float* __restrict__ swl, const float* __restrict__ swr,
                                unsigned short* __restrict__ wt) {
    int gid = blockIdx.x * 256 + threadIdx.x;   // 6*16384
    int m = gid >> 14;
    int e = gid & 16383;
    int k = e >> 7;
    int n = e & 127;
    const float* src = (m == 0) ? gw1 : (m == 1) ? gw2 : (m == 2) ? swl
                     : (m == 3) ? swr : (m == 4) ? (swl + 16384) : (swr + 16384);
    wt[m * 16384 + n * 128 + k] = f2b(src[k * 128 + n]);
}

// ---------------------------------------------------------------------------
// elementwise converts
// ---------------------------------------------------------------------------
__global__ void convert_x_kernel(const float* __restrict__ x, unsigned short* __restrict__ x16, int n) {
    int gid = blockIdx.x * blockDim.x + threadIdx.x;
    int i = gid >> 5, l = gid & 31;
    if (i >= n) return;
    int c0 = l * 4;
    float4 v = *(const float4*)(x + (size_t)i * 128 + c0);
    ushort4 o;
    o.x = f2b(v.x); o.y = f2b(v.y); o.z = f2b(v.z); o.w = f2b(v.w);
    *(ushort4*)(x16 + (size_t)i * 128 + c0) = o;
}

__global__ void convert_xa_kernel(const float* __restrict__ x, const unsigned short* __restrict__ agg16,
                                  unsigned short* __restrict__ xa16, int n) {
    int gid = blockIdx.x * blockDim.x + threadIdx.x;
    int i = gid >> 5, l = gid & 31;
    if (i >= n) return;
    int c0 = l * 4;
    float4 v = *(const float4*)(x + (size_t)i * 128 + c0);
    ushort4 a = *(const ushort4*)(agg16 + (size_t)i * 128 + c0);
    ushort4 o;
    o.x = f2b(v.x + b2f(a.x)); o.y = f2b(v.y + b2f(a.y));
    o.z = f2b(v.z + b2f(a.z)); o.w = f2b(v.w + b2f(a.w));
    *(ushort4*)(xa16 + (size_t)i * 128 + c0) = o;
}

__global__ void convert_h_kernel(const float* __restrict__ hpre, const float* __restrict__ cs,
                                 const float* __restrict__ sh, unsigned short* __restrict__ hb, int n) {
    int gid = blockIdx.x * blockDim.x + threadIdx.x;
    int i = gid >> 5, l = gid & 31;
    if (i >= n) return;
    int c0 = l * 4;
    float4 v = *(const float4*)(hpre + (size_t)i * 128 + c0);
    float4 c = *(const float4*)(cs + c0);
    float4 s = *(const float4*)(sh + c0);
    ushort4 o;
    o.x = f2b(fmaxf(v.x * c.x + s.x, 0.f));
    o.y = f2b(fmaxf(v.y * c.y + s.y, 0.f));
    o.z = f2b(fmaxf(v.z * c.z + s.z, 0.f));
    o.w = f2b(fmaxf(v.w * c.w + s.w, 0.f));
    *(ushort4*)(hb + (size_t)i * 128 + c0) = o;
}

// ---------------------------------------------------------------------------
// bf16 gather aggregation
// ---------------------------------------------------------------------------
template<bool MEAN>
__global__ void csr_aggregate_bf16_kernel(const unsigned short* __restrict__ feat,
                                          const int* __restrict__ row_beg,
                                          const int* __restrict__ row_end,
                                          const int* __restrict__ csr_src,
                                          const float* __restrict__ inv_deg,
                                          unsigned short* __restrict__ agg, int n) {
    int gid = blockIdx.x * blockDim.x + threadIdx.x;
    int node = gid >> 5;
    int lane = gid & 31;
    if (node >= n) return;
    int beg = row_beg[node];
    int end = row_end[node];
    int c0 = lane * 4;
    float a0 = 0.f, a1 = 0.f, a2 = 0.f, a3 = 0.f;
    int e = beg;
    for (; e + 1 < end; e += 2) {
        int s0 = csr_src[e];
        int s1 = csr_src[e + 1];
        ushort4 v0 = *(const ushort4*)(feat + (size_t)s0 * 128 + c0);
        ushort4 v1 = *(const ushort4*)(feat + (size_t)s1 * 128 + c0);
        a0 += b2f(v0.x) + b2f(v1.x);
        a1 += b2f(v0.y) + b2f(v1.y);
        a2 += b2f(v0.z) + b2f(v1.z);
        a3 += b2f(v0.w) + b2f(v1.w);
    }
    if (e < end) {
        int s0 = csr_src[e];
        ushort4 v0 = *(const ushort4*)(feat + (size_t)s0 * 128 + c0);
        a0 += b2f(v0.x); a1 += b2f(v0.y); a2 += b2f(v0.z); a3 += b2f(v0.w);
    }
    if (MEAN) {
        float s = inv_deg[node];
        a0 *= s; a1 *= s; a2 *= s; a3 *= s;
    }
    ushort4 o;
    o.x = f2b(a0); o.y = f2b(a1); o.z = f2b(a2); o.w = f2b(a3);
    *(ushort4*)(agg + (size_t)node * 128 + c0) = o;
}

// ---------------------------------------------------------------------------
// W-stationary register MFMA GEMM.
// Block = 4 waves: wave = (rowpair, colhalf). Each wave: 16 rows x 64 cols.
// W fragments (the wave's 64-col half of W^T, all K) live in registers,
// loaded once; persistent grid-stride over row tiles (32 rows/tile).
//  DUAL:  C = A1@W1 + A2@W2 + bias     else  C = A1@W1 + bias
//  RELUB: C -> relu, bf16 out (Cb)     else  fp32 out (Cf)
//  STATS: per-column sum/sumsq accumulated in regs, one atomic flush at end
// ---------------------------------------------------------------------------
template<bool DUAL, bool RELUB, bool STATS>
__global__ __launch_bounds__(256, 2) void gemm_reg_kernel(
    const unsigned short* __restrict__ A1, const unsigned short* __restrict__ A2,
    const unsigned short* __restrict__ W1t, const unsigned short* __restrict__ W2t,
    const float* __restrict__ bias, float* __restrict__ stats,
    float* __restrict__ Cf, unsigned short* __restrict__ Cb,
    int M, int ntiles)
{
    __shared__ float red[2][128];

    const int t = threadIdx.x;
    const int wave = t >> 6;
    const int lane = t & 63;
    const int colhalf = wave & 1;
    const int rowpair = wave >> 1;
    const int m16 = lane & 15;
    const int quad = lane >> 4;
    const int k0 = quad * 8;
    const int colbase = colhalf * 64;
    const int mycol = colbase + m16;   // + ct*16

    const bf16x8 zero8 = {0, 0, 0, 0, 0, 0, 0, 0};

    // ---- load W fragments once (batched independent loads) ----
    bf16x8 w1f[4][4];
    bf16x8 w2f[4][4];
#pragma unroll
    for (int ct = 0; ct < 4; ct++) {
        int col = mycol + ct * 16;
#pragma unroll
        for (int kc = 0; kc < 4; kc++) {
            w1f[ct][kc] = *(const bf16x8*)(W1t + (size_t)col * 128 + kc * 32 + k0);
            if (DUAL)
                w2f[ct][kc] = *(const bf16x8*)(W2t + (size_t)col * 128 + kc * 32 + k0);
        }
    }

    float psum[4] = {0.f, 0.f, 0.f, 0.f};
    float psq[4]  = {0.f, 0.f, 0.f, 0.f};

    for (int tile = blockIdx.x; tile < ntiles; tile += gridDim.x) {
        int row0 = tile * 32 + rowpair * 16;
        int arow = row0 + m16;
        bool aok = arow < M;

        bf16x8 a1[4], a2[4];
#pragma unroll
        for (int kc = 0; kc < 4; kc++) {
            a1[kc] = aok ? *(const bf16x8*)(A1 + (size_t)arow * 128 + kc * 32 + k0) : zero8;
            if (DUAL)
                a2[kc] = aok ? *(const bf16x8*)(A2 + (size_t)arow * 128 + kc * 32 + k0) : zero8;
        }

        f32x4 acc[4];
#pragma unroll
        for (int ct = 0; ct < 4; ct++) acc[ct] = (f32x4){0.f, 0.f, 0.f, 0.f};

#pragma unroll
        for (int kc = 0; kc < 4; kc++) {
#pragma unroll
            for (int ct = 0; ct < 4; ct++) {
                acc[ct] = __builtin_amdgcn_mfma_f32_16x16x32_bf16(a1[kc], w1f[ct][kc], acc[ct], 0, 0, 0);
                if (DUAL)
                    acc[ct] = __builtin_amdgcn_mfma_f32_16x16x32_bf16(a2[kc], w2f[ct][kc], acc[ct], 0, 0, 0);
            }
        }

        // epilogue (C layout: col = m16-based, row = quad*4 + r)
#pragma unroll
        for (int ct = 0; ct < 4; ct++) {
            int col = mycol + ct * 16;
            float b = bias[col];
#pragma unroll
            for (int r = 0; r < 4; r++) {
                int orow = row0 + quad * 4 + r;
                if (orow < M) {
                    float v = acc[ct][r] + b;
                    if (RELUB) {
                        Cb[(size_t)orow * 128 + col] = f2b(fmaxf(v, 0.f));
                    } else {
                        Cf[(size_t)orow * 128 + col] = v;
                    }
                    if (STATS) { psum[ct] += v; psq[ct] += v * v; }
                }
            }
        }
    }

    if (STATS) {
#pragma unroll
        for (int ct = 0; ct < 4; ct++) {
            psum[ct] += __shfl_down(psum[ct], 32, 64);
            psum[ct] += __shfl_down(psum[ct], 16, 64);
            psq[ct]  += __shfl_down(psq[ct], 32, 64);
            psq[ct]  += __shfl_down(psq[ct], 16, 64);
        }
        if (lane < 16) {
#pragma unroll
            for (int ct = 0; ct < 4; ct++) red[rowpair][mycol + ct * 16] = psum[ct];
        }
        __syncthreads();
        if (t < 128) atomicAdd(&stats[t], red[0][t] + red[1][t]);
        __syncthreads();
        if (lane < 16) {
#pragma unroll
            for (int ct = 0; ct < 4; ct++) red[rowpair][mycol + ct * 16] = psq[ct];
        }
        __syncthreads();
        if (t < 128) atomicAdd(&stats[128 + t], red[0][t] + red[1][t]);
    }
}

// ---------------------------------------------------------------------------
// BN finalize
// ---------------------------------------------------------------------------
__global__ void bn_finalize_kernel(const float* __restrict__ stats,
                                   const float* __restrict__ gamma,
                                   const float* __restrict__ beta,
                                   float* __restrict__ cs, float* __restrict__ sh) {
    int t = threadIdx.x;
    if (t >= 128) return;
    float inv_n = 1.0f / (float)N_NODES;
    float mu = stats[t] * inv_n;
    float var = stats[128 + t] * inv_n - mu * mu;
    float rs = rsqrtf(var + BN_EPS);
    float c = gamma[t] * rs;
    cs[t] = c;
    sh[t] = beta[t] - mu * c;
}

// ---------------------------------------------------------------------------
// global mean pool (fused BN affine + relu)
// ---------------------------------------------------------------------------
__global__ void gstart_kernel(const int* __restrict__ batch, int* __restrict__ gstart, int n) {
    int g = blockIdx.x * blockDim.x + threadIdx.x;
    if (g > N_GRAPHS) return;
    int lo = 0, hi = n;
    while (lo < hi) {
        int mid = (lo + hi) >> 1;
        if (batch[mid] < g) lo = mid + 1; else hi = mid;
    }
    gstart[g] = lo;
}

__global__ __launch_bounds__(128) void pool_mean_kernel(const float* __restrict__ h,
                                                        const int* __restrict__ gstart,
                                                        const float* __restrict__ cs,
                                                        const float* __restrict__ sh,
                                                        float* __restrict__ out) {
    int g = blockIdx.x;
    int col = threadIdx.x;
    int beg = gstart[g];
    int end = gstart[g + 1];
    float c = cs[col], b = sh[col];
    float s = 0.f;
    for (int i = beg; i < end; i++)
        s += fmaxf(h[(size_t)i * 128 + col] * c + b, 0.f);
    float cnt = fmaxf((float)(end - beg), 1.0f);
    out[(size_t)g * 128 + col] = s / cnt;
}

// ---------------------------------------------------------------------------
extern "C" void kernel_launch(void* const* d_in, const int* in_sizes, int n_in,
                              void* d_out, int out_size, void* d_ws, size_t ws_size,
                              hipStream_t stream) {
    const float* x    = (const float*)d_in[0];
    const int*   ei   = (const int*)d_in[1];
    const int*   src  = ei;
    const int*   dst  = ei + N_EDGES;
    const int*   batch = (const int*)d_in[2];
    const float* gw1  = (const float*)d_in[3];
    const float* gb1  = (const float*)d_in[4];
    const float* gw2  = (const float*)d_in[5];
    const float* gb2  = (const float*)d_in[6];
    const float* swl  = (const float*)d_in[7];
    const float* sbl  = (const float*)d_in[8];
    const float* swr  = (const float*)d_in[9];
    const float* bng  = (const float*)d_in[10];
    const float* bnb  = (const float*)d_in[11];
    float* out = (float*)d_out;

    // workspace (float units)
    float* ws = (float*)d_ws;
    float*          hpre   = ws;                              // 6.4M fp32
    unsigned short* agg16  = (unsigned short*)(ws + 6400000);
    unsigned short* hx16   = (unsigned short*)(ws + 9600000);
    unsigned short* x16    = (unsigned short*)(ws + 12800000); // x16, then T1
    unsigned short* wt     = (unsigned short*)(ws + 16000000); // 6*16384 u16
    float*          inv_deg= ws + 16050000;
    float*          stats  = ws + 16100000;                   // 3*256
    float*          cs     = ws + 16100768;
    float*          sh     = ws + 16101152;
    int*            row_beg= (int*)(ws + 16101536);
    int*            cursor = (int*)(ws + 16151536);
    int*            csr_src= (int*)(ws + 16201536);
    int*            gstart = (int*)(ws + 16801536);
    int*            total  = (int*)(ws + 16802049);

    const int elem_blocks = (N_NODES * 32 + 255) / 256;
    const int ntiles = (N_NODES + 31) / 32;                   // 1563
    const int ggrid = 1024;

    // ---- CSR build ----
    hipMemsetAsync(cursor, 0, N_NODES * sizeof(int), stream);
    hipMemsetAsync(total, 0, sizeof(int), stream);
    hipMemsetAsync(stats, 0, 3 * 256 * sizeof(float), stream);
    deg_count_kernel<<<(N_EDGES + 255) / 256, 256, 0, stream>>>(dst, cursor, N_EDGES);
    alloc_kernel<<<(N_NODES + 255) / 256, 256, 0, stream>>>(cursor, row_beg, inv_deg, total, N_NODES);
    csr_fill_kernel<<<(N_EDGES + 255) / 256, 256, 0, stream>>>(src, dst, cursor, csr_src, N_EDGES);
    gstart_kernel<<<3, 256, 0, stream>>>(batch, gstart, N_NODES);

    // ---- weights -> bf16 transposed ----
    wconvert_kernel<<<(6 * 16384) / 256, 256, 0, stream>>>(gw1, gw2, swl, swr, wt);

    // ---- GIN ----
    convert_x_kernel<<<elem_blocks, 256, 0, stream>>>(x, x16, N_NODES);
    csr_aggregate_bf16_kernel<false><<<elem_blocks, 256, 0, stream>>>(
        x16, row_beg, cursor, csr_src, nullptr, agg16, N_NODES);
    convert_xa_kernel<<<elem_blocks, 256, 0, stream>>>(x, agg16, hx16, N_NODES);
    // GIN GEMM 1: T1 = relu(xa@W1+b1) -> bf16 (reuse x16)
    gemm_reg_kernel<false, true, false><<<ggrid, 256, 0, stream>>>(
        hx16, nullptr, wt + 0 * 16384, nullptr, gb1, nullptr, nullptr, x16, N_NODES, ntiles);
    // GIN GEMM 2: hpre = T1@W2+b2 (+stats)
    gemm_reg_kernel<false, false, true><<<ggrid, 256, 0, stream>>>(
        x16, nullptr, wt + 1 * 16384, nullptr, gb2, stats + 0, hpre, nullptr, N_NODES, ntiles);
    bn_finalize_kernel<<<1, 128, 0, stream>>>(stats + 0, bng + 0 * HID, bnb + 0 * HID, cs + 0, sh + 0);

    // ---- SAGE 0 ----
    convert_h_kernel<<<elem_blocks, 256, 0, stream>>>(hpre, cs + 0, sh + 0, hx16, N_NODES);
    csr_aggregate_bf16_kernel<true><<<elem_blocks, 256, 0, stream>>>(
        hx16, row_beg, cursor, csr_src, inv_deg, agg16, N_NODES);
    gemm_reg_kernel<true, false, true><<<ggrid, 256, 0, stream>>>(
        agg16, hx16, wt + 2 * 16384, wt + 3 * 16384, sbl + 0 * HID, stats + 256, hpre, nullptr, N_NODES, ntiles);
    bn_finalize_kernel<<<1, 128, 0, stream>>>(stats + 256, bng + 1 * HID, bnb + 1 * HID, cs + 128, sh + 128);

    // ---- SAGE 1 ----
    convert_h_kernel<<<elem_blocks, 256, 0, stream>>>(hpre, cs + 128, sh + 128, hx16, N_NODES);
    csr_aggregate_bf16_kernel<true><<<elem_blocks, 256, 0, stream>>>(
        hx16, row_beg, cursor, csr_src, inv_deg, agg16, N_NODES);
    gemm_reg_kernel<true, false, true><<<ggrid, 256, 0, stream>>>(
        agg16, hx16, wt + 4 * 16384, wt + 5 * 16384, sbl + 1 * HID, stats + 512, hpre, nullptr, N_NODES, ntiles);
    bn_finalize_kernel<<<1, 128, 0, stream>>>(stats + 512, bng + 2 * HID, bnb + 2 * HID, cs + 256, sh + 256);

    // ---- pool ----
    pool_mean_kernel<<<N_GRAPHS, 128, 0, stream>>>(hpre, gstart, cs + 256, sh + 256, out);
}

// Round 9
// 415.633 us; speedup vs baseline: 1.3623x; 1.0980x over previous
//
#include <hip/hip_runtime.h>

#define N_NODES 50000
#define N_EDGES 600000
#define HID 128
#define N_GRAPHS 512
#define BN_EPS 1e-5f

typedef __attribute__((ext_vector_type(8))) short bf16x8;
typedef __attribute__((ext_vector_type(4))) float f32x4;

__device__ __forceinline__ unsigned short f2b(float f) {
    unsigned u = __float_as_uint(f);
    return (unsigned short)((u + 0x7FFFu + ((u >> 16) & 1u)) >> 16);
}
__device__ __forceinline__ float b2f(unsigned short h) {
    return __uint_as_float(((unsigned)h) << 16);
}

// ---------------------------------------------------------------------------
// CSR build
// ---------------------------------------------------------------------------
__global__ void deg_count_kernel(const int* __restrict__ dst, int* __restrict__ deg, int nE) {
    int e = blockIdx.x * blockDim.x + threadIdx.x;
    if (e < nE) atomicAdd(&deg[dst[e]], 1);
}

__global__ __launch_bounds__(256) void alloc_kernel(int* __restrict__ cursor,
                                                    int* __restrict__ row_beg,
                                                    float* __restrict__ inv_deg,
                                                    int* __restrict__ total, int n) {
    __shared__ int tmp[256];
    __shared__ int base;
    int i = blockIdx.x * 256 + threadIdx.x;
    int d = (i < n) ? cursor[i] : 0;
    tmp[threadIdx.x] = d;
    __syncthreads();
#pragma unroll
    for (int off = 1; off < 256; off <<= 1) {
        int v = (threadIdx.x >= off) ? tmp[threadIdx.x - off] : 0;
        __syncthreads();
        tmp[threadIdx.x] += v;
        __syncthreads();
    }
    if (threadIdx.x == 255) base = atomicAdd(total, tmp[255]);
    __syncthreads();
    if (i < n) {
        int b = base + tmp[threadIdx.x] - d;
        row_beg[i] = b;
        cursor[i] = b;
        inv_deg[i] = 1.0f / fmaxf((float)d, 1.0f);
    }
}

__global__ void csr_fill_kernel(const int* __restrict__ src, const int* __restrict__ dst,
                                int* __restrict__ cursor, int* __restrict__ csr_src, int nE) {
    int e = blockIdx.x * blockDim.x + threadIdx.x;
    if (e < nE) {
        int pos = atomicAdd(&cursor[dst[e]], 1);
        csr_src[pos] = src[e];
    }
}

// ---------------------------------------------------------------------------
// weight transpose + bf16 convert: wt[m][n][k] = bf16(W_m[k][n]), 6 matrices
// ---------------------------------------------------------------------------
__global__ void wconvert_kernel(const float* __restrict__ gw1, const float* __restrict__ gw2,
                                const float* __restrict__ swl, const float* __restrict__ swr,
                                unsigned short* __restrict__ wt) {
    int gid = blockIdx.x * 256 + threadIdx.x;   // 6*16384
    int m = gid >> 14;
    int e = gid & 16383;
    int k = e >> 7;
    int n = e & 127;
    const float* src = (m == 0) ? gw1 : (m == 1) ? gw2 : (m == 2) ? swl
                     : (m == 3) ? swr : (m == 4) ? (swl + 16384) : (swr + 16384);
    wt[m * 16384 + n * 128 + k] = f2b(src[k * 128 + n]);
}

// ---------------------------------------------------------------------------
// elementwise converts
// ---------------------------------------------------------------------------
__global__ void convert_x_kernel(const float* __restrict__ x, unsigned short* __restrict__ x16, int n) {
    int gid = blockIdx.x * blockDim.x + threadIdx.x;
    int i = gid >> 5, l = gid & 31;
    if (i >= n) return;
    int c0 = l * 4;
    float4 v = *(const float4*)(x + (size_t)i * 128 + c0);
    ushort4 o;
    o.x = f2b(v.x); o.y = f2b(v.y); o.z = f2b(v.z); o.w = f2b(v.w);
    *(ushort4*)(x16 + (size_t)i * 128 + c0) = o;
}

__global__ void convert_h_kernel(const float* __restrict__ hpre, const float* __restrict__ cs,
                                 const float* __restrict__ sh, unsigned short* __restrict__ hb, int n) {
    int gid = blockIdx.x * blockDim.x + threadIdx.x;
    int i = gid >> 5, l = gid & 31;
    if (i >= n) return;
    int c0 = l * 4;
    float4 v = *(const float4*)(hpre + (size_t)i * 128 + c0);
    float4 c = *(const float4*)(cs + c0);
    float4 s = *(const float4*)(sh + c0);
    ushort4 o;
    o.x = f2b(fmaxf(v.x * c.x + s.x, 0.f));
    o.y = f2b(fmaxf(v.y * c.y + s.y, 0.f));
    o.z = f2b(fmaxf(v.z * c.z + s.z, 0.f));
    o.w = f2b(fmaxf(v.w * c.w + s.w, 0.f));
    *(ushort4*)(hb + (size_t)i * 128 + c0) = o;
}

// ---------------------------------------------------------------------------
// bf16 gather aggregation
// ---------------------------------------------------------------------------
template<bool MEAN>
__global__ void csr_aggregate_bf16_kernel(const unsigned short* __restrict__ feat,
                                          const int* __restrict__ row_beg,
                                          const int* __restrict__ row_end,
                                          const int* __restrict__ csr_src,
                                          const float* __restrict__ inv_deg,
                                          unsigned short* __restrict__ agg, int n) {
    int gid = blockIdx.x * blockDim.x + threadIdx.x;
    int node = gid >> 5;
    int lane = gid & 31;
    if (node >= n) return;
    int beg = row_beg[node];
    int end = row_end[node];
    int c0 = lane * 4;
    float a0 = 0.f, a1 = 0.f, a2 = 0.f, a3 = 0.f;
    int e = beg;
    for (; e + 1 < end; e += 2) {
        int s0 = csr_src[e];
        int s1 = csr_src[e + 1];
        ushort4 v0 = *(const ushort4*)(feat + (size_t)s0 * 128 + c0);
        ushort4 v1 = *(const ushort4*)(feat + (size_t)s1 * 128 + c0);
        a0 += b2f(v0.x) + b2f(v1.x);
        a1 += b2f(v0.y) + b2f(v1.y);
        a2 += b2f(v0.z) + b2f(v1.z);
        a3 += b2f(v0.w) + b2f(v1.w);
    }
    if (e < end) {
        int s0 = csr_src[e];
        ushort4 v0 = *(const ushort4*)(feat + (size_t)s0 * 128 + c0);
        a0 += b2f(v0.x); a1 += b2f(v0.y); a2 += b2f(v0.z); a3 += b2f(v0.w);
    }
    if (MEAN) {
        float s = inv_deg[node];
        a0 *= s; a1 *= s; a2 *= s; a3 *= s;
    }
    ushort4 o;
    o.x = f2b(a0); o.y = f2b(a1); o.z = f2b(a2); o.w = f2b(a3);
    *(ushort4*)(agg + (size_t)node * 128 + c0) = o;
}

// ---------------------------------------------------------------------------
// Single-matrix W-stationary MFMA GEMM with swapped operands:
//   mfma(w_frag, a_frag, acc) -> thread owns row (m16), cols ct*16+quad*4..+3
//   => coalesced float4/ushort4 stores; shfl_xor stats reduction.
// Wave = 16 rows x 64 cols (colhalf); block = 2 rowpairs x 2 colhalves = 32-row tile.
// AMODE 0: A = bf16 array (prefetch-pipelined)
// AMODE 1: A = bf16(x_fp32 + agg_bf16) built in-register (GIN layer-1 fusion)
// RELUB: out = relu -> bf16 (Cb);  else fp32 (Cf) [+ STATS col sums/sumsq]
// ---------------------------------------------------------------------------
template<int AMODE, bool RELUB, bool STATS>
__global__ __launch_bounds__(256) void gemm_single_kernel(
    const float* __restrict__ xf, const unsigned short* __restrict__ A1,
    const unsigned short* __restrict__ Wt, const float* __restrict__ bias,
    float* __restrict__ stats, float* __restrict__ Cf, unsigned short* __restrict__ Cb,
    int M, int ntiles)
{
    __shared__ float red[2][128];

    const int t = threadIdx.x;
    const int wave = t >> 6;
    const int lane = t & 63;
    const int colhalf = wave & 1;
    const int rowpair = wave >> 1;
    const int m16 = lane & 15;
    const int quad = lane >> 4;
    const int k0 = quad * 8;
    const int colbase = colhalf * 64;

    const bf16x8 zero8 = {0, 0, 0, 0, 0, 0, 0, 0};

    // W fragments (held for whole kernel)
    bf16x8 wf[4][4];
#pragma unroll
    for (int ct = 0; ct < 4; ct++) {
        int col = colbase + ct * 16 + m16;
#pragma unroll
        for (int kc = 0; kc < 4; kc++)
            wf[ct][kc] = *(const bf16x8*)(Wt + (size_t)col * 128 + kc * 32 + k0);
    }
    f32x4 bs[4];
#pragma unroll
    for (int ct = 0; ct < 4; ct++)
        bs[ct] = *(const f32x4*)(bias + colbase + ct * 16 + quad * 4);

    float psum[4][4], psq[4][4];
    if (STATS) {
#pragma unroll
        for (int ct = 0; ct < 4; ct++)
#pragma unroll
            for (int r = 0; r < 4; r++) { psum[ct][r] = 0.f; psq[ct][r] = 0.f; }
    }

    bf16x8 a[4], an[4];

    int tile = blockIdx.x;
    if (AMODE == 0 && tile < ntiles) {
        int arow = tile * 32 + rowpair * 16 + m16;
        bool aok = arow < M;
#pragma unroll
        for (int kc = 0; kc < 4; kc++)
            a[kc] = aok ? *(const bf16x8*)(A1 + (size_t)arow * 128 + kc * 32 + k0) : zero8;
    }

    for (; tile < ntiles; tile += gridDim.x) {
        int nt = tile + gridDim.x;
        if (AMODE == 1) {
            int arow = tile * 32 + rowpair * 16 + m16;
            bool aok = arow < M;
#pragma unroll
            for (int kc = 0; kc < 4; kc++) {
                if (aok) {
                    float4 x0 = *(const float4*)(xf + (size_t)arow * 128 + kc * 32 + k0);
                    float4 x1 = *(const float4*)(xf + (size_t)arow * 128 + kc * 32 + k0 + 4);
                    bf16x8 g = *(const bf16x8*)(A1 + (size_t)arow * 128 + kc * 32 + k0);
                    bf16x8 r;
                    r[0] = (short)f2b(x0.x + b2f((unsigned short)g[0]));
                    r[1] = (short)f2b(x0.y + b2f((unsigned short)g[1]));
                    r[2] = (short)f2b(x0.z + b2f((unsigned short)g[2]));
                    r[3] = (short)f2b(x0.w + b2f((unsigned short)g[3]));
                    r[4] = (short)f2b(x1.x + b2f((unsigned short)g[4]));
                    r[5] = (short)f2b(x1.y + b2f((unsigned short)g[5]));
                    r[6] = (short)f2b(x1.z + b2f((unsigned short)g[6]));
                    r[7] = (short)f2b(x1.w + b2f((unsigned short)g[7]));
                    a[kc] = r;
                } else {
                    a[kc] = zero8;
                }
            }
        } else if (nt < ntiles) {
            int arow = nt * 32 + rowpair * 16 + m16;
            bool aok = arow < M;
#pragma unroll
            for (int kc = 0; kc < 4; kc++)
                an[kc] = aok ? *(const bf16x8*)(A1 + (size_t)arow * 128 + kc * 32 + k0) : zero8;
        }

        f32x4 acc[4];
#pragma unroll
        for (int ct = 0; ct < 4; ct++) acc[ct] = (f32x4){0.f, 0.f, 0.f, 0.f};
#pragma unroll
        for (int kc = 0; kc < 4; kc++)
#pragma unroll
            for (int ct = 0; ct < 4; ct++)
                acc[ct] = __builtin_amdgcn_mfma_f32_16x16x32_bf16(wf[ct][kc], a[kc], acc[ct], 0, 0, 0);

        int orow = tile * 32 + rowpair * 16 + m16;
        if (orow < M) {
#pragma unroll
            for (int ct = 0; ct < 4; ct++) {
                f32x4 v = acc[ct] + bs[ct];
                int col = colbase + ct * 16 + quad * 4;
                if (RELUB) {
                    ushort4 o;
                    o.x = f2b(fmaxf(v[0], 0.f));
                    o.y = f2b(fmaxf(v[1], 0.f));
                    o.z = f2b(fmaxf(v[2], 0.f));
                    o.w = f2b(fmaxf(v[3], 0.f));
                    *(ushort4*)(Cb + (size_t)orow * 128 + col) = o;
                } else {
                    *(f32x4*)(Cf + (size_t)orow * 128 + col) = v;
                    if (STATS) {
#pragma unroll
                        for (int r = 0; r < 4; r++) { psum[ct][r] += v[r]; psq[ct][r] += v[r] * v[r]; }
                    }
                }
            }
        }

        if (AMODE == 0 && nt < ntiles) {
            a[0] = an[0]; a[1] = an[1]; a[2] = an[2]; a[3] = an[3];
        }
    }

    if (STATS) {
#pragma unroll
        for (int ct = 0; ct < 4; ct++)
#pragma unroll
            for (int r = 0; r < 4; r++) {
#pragma unroll
                for (int mask = 1; mask <= 8; mask <<= 1) {
                    psum[ct][r] += __shfl_xor(psum[ct][r], mask, 64);
                    psq[ct][r]  += __shfl_xor(psq[ct][r], mask, 64);
                }
            }
        if (m16 == 0) {
#pragma unroll
            for (int ct = 0; ct < 4; ct++)
#pragma unroll
                for (int r = 0; r < 4; r++)
                    red[rowpair][colbase + ct * 16 + quad * 4 + r] = psum[ct][r];
        }
        __syncthreads();
        if (t < 128) atomicAdd(&stats[t], red[0][t] + red[1][t]);
        __syncthreads();
        if (m16 == 0) {
#pragma unroll
            for (int ct = 0; ct < 4; ct++)
#pragma unroll
                for (int r = 0; r < 4; r++)
                    red[rowpair][colbase + ct * 16 + quad * 4 + r] = psq[ct][r];
        }
        __syncthreads();
        if (t < 128) atomicAdd(&stats[128 + t], red[0][t] + red[1][t]);
    }
}

// ---------------------------------------------------------------------------
// Dual-matrix GEMM (SAGE): C = A1@W1 + A2@W2 + bias, fp32 out + stats.
// Wave = 16 rows x 32 cols (col quarter); all 4 waves load the SAME A rows
// (L1 broadcast). Tile = 16 rows; A1/A2 both prefetch-pipelined.
// ---------------------------------------------------------------------------
__global__ __launch_bounds__(256) void gemm_dual_kernel(
    const unsigned short* __restrict__ A1, const unsigned short* __restrict__ A2,
    const unsigned short* __restrict__ W1t, const unsigned short* __restrict__ W2t,
    const float* __restrict__ bias, float* __restrict__ stats,
    float* __restrict__ Cf, int M, int ntiles)
{
    __shared__ float red[128];

    const int t = threadIdx.x;
    const int wave = t >> 6;
    const int lane = t & 63;
    const int m16 = lane & 15;
    const int quad = lane >> 4;
    const int k0 = quad * 8;
    const int colbase = wave * 32;

    const bf16x8 zero8 = {0, 0, 0, 0, 0, 0, 0, 0};

    bf16x8 w1f[2][4], w2f[2][4];
#pragma unroll
    for (int ct = 0; ct < 2; ct++) {
        int col = colbase + ct * 16 + m16;
#pragma unroll
        for (int kc = 0; kc < 4; kc++) {
            w1f[ct][kc] = *(const bf16x8*)(W1t + (size_t)col * 128 + kc * 32 + k0);
            w2f[ct][kc] = *(const bf16x8*)(W2t + (size_t)col * 128 + kc * 32 + k0);
        }
    }
    f32x4 bs[2];
#pragma unroll
    for (int ct = 0; ct < 2; ct++)
        bs[ct] = *(const f32x4*)(bias + colbase + ct * 16 + quad * 4);

    float psum[2][4], psq[2][4];
#pragma unroll
    for (int ct = 0; ct < 2; ct++)
#pragma unroll
        for (int r = 0; r < 4; r++) { psum[ct][r] = 0.f; psq[ct][r] = 0.f; }

    bf16x8 a1[4], a2[4], a1n[4], a2n[4];

    int tile = blockIdx.x;
    if (tile < ntiles) {
        int arow = tile * 16 + m16;
        bool aok = arow < M;
#pragma unroll
        for (int kc = 0; kc < 4; kc++) {
            a1[kc] = aok ? *(const bf16x8*)(A1 + (size_t)arow * 128 + kc * 32 + k0) : zero8;
            a2[kc] = aok ? *(const bf16x8*)(A2 + (size_t)arow * 128 + kc * 32 + k0) : zero8;
        }
    }

    for (; tile < ntiles; tile += gridDim.x) {
        int nt = tile + gridDim.x;
        if (nt < ntiles) {
            int arow = nt * 16 + m16;
            bool aok = arow < M;
#pragma unroll
            for (int kc = 0; kc < 4; kc++) {
                a1n[kc] = aok ? *(const bf16x8*)(A1 + (size_t)arow * 128 + kc * 32 + k0) : zero8;
                a2n[kc] = aok ? *(const bf16x8*)(A2 + (size_t)arow * 128 + kc * 32 + k0) : zero8;
            }
        }

        f32x4 acc[2];
        acc[0] = (f32x4){0.f, 0.f, 0.f, 0.f};
        acc[1] = (f32x4){0.f, 0.f, 0.f, 0.f};
#pragma unroll
        for (int kc = 0; kc < 4; kc++) {
#pragma unroll
            for (int ct = 0; ct < 2; ct++) {
                acc[ct] = __builtin_amdgcn_mfma_f32_16x16x32_bf16(w1f[ct][kc], a1[kc], acc[ct], 0, 0, 0);
                acc[ct] = __builtin_amdgcn_mfma_f32_16x16x32_bf16(w2f[ct][kc], a2[kc], acc[ct], 0, 0, 0);
            }
        }

        int orow = tile * 16 + m16;
        if (orow < M) {
#pragma unroll
            for (int ct = 0; ct < 2; ct++) {
                f32x4 v = acc[ct] + bs[ct];
                int col = colbase + ct * 16 + quad * 4;
                *(f32x4*)(Cf + (size_t)orow * 128 + col) = v;
#pragma unroll
                for (int r = 0; r < 4; r++) { psum[ct][r] += v[r]; psq[ct][r] += v[r] * v[r]; }
            }
        }

        if (nt < ntiles) {
            a1[0] = a1n[0]; a1[1] = a1n[1]; a1[2] = a1n[2]; a1[3] = a1n[3];
            a2[0] = a2n[0]; a2[1] = a2n[1]; a2[2] = a2n[2]; a2[3] = a2n[3];
        }
    }

    // stats flush: reduce across m16 lanes, waves own disjoint 32-col quarters
#pragma unroll
    for (int ct = 0; ct < 2; ct++)
#pragma unroll
        for (int r = 0; r < 4; r++) {
#pragma unroll
            for (int mask = 1; mask <= 8; mask <<= 1) {
                psum[ct][r] += __shfl_xor(psum[ct][r], mask, 64);
                psq[ct][r]  += __shfl_xor(psq[ct][r], mask, 64);
            }
        }
    if (m16 == 0) {
#pragma unroll
        for (int ct = 0; ct < 2; ct++)
#pragma unroll
            for (int r = 0; r < 4; r++)
                red[colbase + ct * 16 + quad * 4 + r] = psum[ct][r];
    }
    __syncthreads();
    if (t < 128) atomicAdd(&stats[t], red[t]);
    __syncthreads();
    if (m16 == 0) {
#pragma unroll
        for (int ct = 0; ct < 2; ct++)
#pragma unroll
            for (int r = 0; r < 4; r++)
                red[colbase + ct * 16 + quad * 4 + r] = psq[ct][r];
    }
    __syncthreads();
    if (t < 128) atomicAdd(&stats[128 + t], red[t]);
}

// ---------------------------------------------------------------------------
// BN finalize
// ---------------------------------------------------------------------------
__global__ void bn_finalize_kernel(const float* __restrict__ stats,
                                   const float* __restrict__ gamma,
                                   const float* __restrict__ beta,
                                   float* __restrict__ cs, float* __restrict__ sh) {
    int t = threadIdx.x;
    if (t >= 128) return;
    float inv_n = 1.0f / (float)N_NODES;
    float mu = stats[t] * inv_n;
    float var = stats[128 + t] * inv_n - mu * mu;
    float rs = rsqrtf(var + BN_EPS);
    float c = gamma[t] * rs;
    cs[t] = c;
    sh[t] = beta[t] - mu * c;
}

// ---------------------------------------------------------------------------
// global mean pool (fused BN affine + relu)
// ---------------------------------------------------------------------------
__global__ void gstart_kernel(const int* __restrict__ batch, int* __restrict__ gstart, int n) {
    int g = blockIdx.x * blockDim.x + threadIdx.x;
    if (g > N_GRAPHS) return;
    int lo = 0, hi = n;
    while (lo < hi) {
        int mid = (lo + hi) >> 1;
        if (batch[mid] < g) lo = mid + 1; else hi = mid;
    }
    gstart[g] = lo;
}

__global__ __launch_bounds__(128) void pool_mean_kernel(const float* __restrict__ h,
                                                        const int* __restrict__ gstart,
                                                        const float* __restrict__ cs,
                                                        const float* __restrict__ sh,
                                                        float* __restrict__ out) {
    int g = blockIdx.x;
    int col = threadIdx.x;
    int beg = gstart[g];
    int end = gstart[g + 1];
    float c = cs[col], b = sh[col];
    float s = 0.f;
    for (int i = beg; i < end; i++)
        s += fmaxf(h[(size_t)i * 128 + col] * c + b, 0.f);
    float cnt = fmaxf((float)(end - beg), 1.0f);
    out[(size_t)g * 128 + col] = s / cnt;
}

// ---------------------------------------------------------------------------
extern "C" void kernel_launch(void* const* d_in, const int* in_sizes, int n_in,
                              void* d_out, int out_size, void* d_ws, size_t ws_size,
                              hipStream_t stream) {
    const float* x    = (const float*)d_in[0];
    const int*   ei   = (const int*)d_in[1];
    const int*   src  = ei;
    const int*   dst  = ei + N_EDGES;
    const int*   batch = (const int*)d_in[2];
    const float* gw1  = (const float*)d_in[3];
    const float* gb1  = (const float*)d_in[4];
    const float* gw2  = (const float*)d_in[5];
    const float* gb2  = (const float*)d_in[6];
    const float* swl  = (const float*)d_in[7];
    const float* sbl  = (const float*)d_in[8];
    const float* swr  = (const float*)d_in[9];
    const float* bng  = (const float*)d_in[10];
    const float* bnb  = (const float*)d_in[11];
    float* out = (float*)d_out;

    // workspace (float units)
    float* ws = (float*)d_ws;
    float*          hpre   = ws;                              // 6.4M fp32
    unsigned short* agg16  = (unsigned short*)(ws + 6400000);
    unsigned short* hx16   = (unsigned short*)(ws + 9600000);
    unsigned short* x16    = (unsigned short*)(ws + 12800000); // x16, then T1
    unsigned short* wt     = (unsigned short*)(ws + 16000000); // 6*16384 u16
    float*          inv_deg= ws + 16050000;
    float*          stats  = ws + 16100000;                   // 3*256
    float*          cs     = ws + 16100768;
    float*          sh     = ws + 16101152;
    int*            row_beg= (int*)(ws + 16101536);
    int*            cursor = (int*)(ws + 16151536);
    int*            csr_src= (int*)(ws + 16201536);
    int*            gstart = (int*)(ws + 16801536);
    int*            total  = (int*)(ws + 16802049);

    const int elem_blocks = (N_NODES * 32 + 255) / 256;
    const int ntiles32 = (N_NODES + 31) / 32;                 // 1563
    const int ntiles16 = (N_NODES + 15) / 16;                 // 3125
    const int ggrid = 512;

    // ---- CSR build ----
    hipMemsetAsync(cursor, 0, N_NODES * sizeof(int), stream);
    hipMemsetAsync(total, 0, sizeof(int), stream);
    hipMemsetAsync(stats, 0, 3 * 256 * sizeof(float), stream);
    deg_count_kernel<<<(N_EDGES + 255) / 256, 256, 0, stream>>>(dst, cursor, N_EDGES);
    alloc_kernel<<<(N_NODES + 255) / 256, 256, 0, stream>>>(cursor, row_beg, inv_deg, total, N_NODES);
    csr_fill_kernel<<<(N_EDGES + 255) / 256, 256, 0, stream>>>(src, dst, cursor, csr_src, N_EDGES);
    gstart_kernel<<<3, 256, 0, stream>>>(batch, gstart, N_NODES);

    // ---- weights -> bf16 transposed ----
    wconvert_kernel<<<(6 * 16384) / 256, 256, 0, stream>>>(gw1, gw2, swl, swr, wt);

    // ---- GIN ----
    convert_x_kernel<<<elem_blocks, 256, 0, stream>>>(x, x16, N_NODES);
    csr_aggregate_bf16_kernel<false><<<elem_blocks, 256, 0, stream>>>(
        x16, row_beg, cursor, csr_src, nullptr, agg16, N_NODES);
    // GIN GEMM 1 (fused x+agg convert): T1 = relu((x+agg)@W1+b1) -> bf16, reuse x16
    gemm_single_kernel<1, true, false><<<ggrid, 256, 0, stream>>>(
        x, agg16, wt + 0 * 16384, gb1, nullptr, nullptr, x16, N_NODES, ntiles32);
    // GIN GEMM 2: hpre = T1@W2+b2 (+stats)
    gemm_single_kernel<0, false, true><<<ggrid, 256, 0, stream>>>(
        nullptr, x16, wt + 1 * 16384, gb2, stats + 0, hpre, nullptr, N_NODES, ntiles32);
    bn_finalize_kernel<<<1, 128, 0, stream>>>(stats + 0, bng + 0 * HID, bnb + 0 * HID, cs + 0, sh + 0);

    // ---- SAGE 0 ----
    convert_h_kernel<<<elem_blocks, 256, 0, stream>>>(hpre, cs + 0, sh + 0, hx16, N_NODES);
    csr_aggregate_bf16_kernel<true><<<elem_blocks, 256, 0, stream>>>(
        hx16, row_beg, cursor, csr_src, inv_deg, agg16, N_NODES);
    gemm_dual_kernel<<<ggrid, 256, 0, stream>>>(
        agg16, hx16, wt + 2 * 16384, wt + 3 * 16384, sbl + 0 * HID, stats + 256, hpre, N_NODES, ntiles16);
    bn_finalize_kernel<<<1, 128, 0, stream>>>(stats + 256, bng + 1 * HID, bnb + 1 * HID, cs + 128, sh + 128);

    // ---- SAGE 1 ----
    convert_h_kernel<<<elem_blocks, 256, 0, stream>>>(hpre, cs + 128, sh + 128, hx16, N_NODES);
    csr_aggregate_bf16_kernel<true><<<elem_blocks, 256, 0, stream>>>(
        hx16, row_beg, cursor, csr_src, inv_deg, agg16, N_NODES);
    gemm_dual_kernel<<<ggrid, 256, 0, stream>>>(
        agg16, hx16, wt + 4 * 16384, wt + 5 * 16384, sbl + 1 * HID, stats + 512, hpre, N_NODES, ntiles16);
    bn_finalize_kernel<<<1, 128, 0, stream>>>(stats + 512, bng + 2 * HID, bnb + 2 * HID, cs + 256, sh + 256);

    // ---- pool ----
    pool_mean_kernel<<<N_GRAPHS, 128, 0, stream>>>(hpre, gstart, cs + 256, sh + 256, out);
}

// Round 10
// 384.525 us; speedup vs baseline: 1.4726x; 1.0809x over previous
//
#include <hip/hip_runtime.h>

#define N_NODES 50000
#define N_EDGES 600000
#define HID 128
#define N_GRAPHS 512
#define BN_EPS 1e-5f
#define INV_N (1.0f / 50000.0f)

typedef __attribute__((ext_vector_type(8))) short bf16x8;
typedef __attribute__((ext_vector_type(4))) float f32x4;

__device__ __forceinline__ unsigned short f2b(float f) {
    unsigned u = __float_as_uint(f);
    return (unsigned short)((u + 0x7FFFu + ((u >> 16) & 1u)) >> 16);
}
__device__ __forceinline__ float b2f(unsigned short h) {
    return __uint_as_float(((unsigned)h) << 16);
}

// ---------------------------------------------------------------------------
// prep: convert x -> bf16 | transpose+convert 6 weight mats | degree count
// ---------------------------------------------------------------------------
#define CONVX_BLOCKS 6250
#define WCONV_BLOCKS 384
#define DEG_BLOCKS   2344
__global__ __launch_bounds__(256) void prep_kernel(
    const float* __restrict__ x, const float* __restrict__ gw1, const float* __restrict__ gw2,
    const float* __restrict__ swl, const float* __restrict__ swr, const int* __restrict__ dst,
    unsigned short* __restrict__ x16, unsigned short* __restrict__ wt, int* __restrict__ deg)
{
    int b = blockIdx.x;
    int t = threadIdx.x;
    if (b < CONVX_BLOCKS) {
        int gid = b * 256 + t;
        int i = gid >> 5, l = gid & 31;
        if (i >= N_NODES) return;
        int c0 = l * 4;
        float4 v = *(const float4*)(x + (size_t)i * 128 + c0);
        ushort4 o;
        o.x = f2b(v.x); o.y = f2b(v.y); o.z = f2b(v.z); o.w = f2b(v.w);
        *(ushort4*)(x16 + (size_t)i * 128 + c0) = o;
    } else if (b < CONVX_BLOCKS + WCONV_BLOCKS) {
        int gid = (b - CONVX_BLOCKS) * 256 + t;   // < 6*16384
        int m = gid >> 14;
        int e = gid & 16383;
        int k = e >> 7;
        int n = e & 127;
        const float* src = (m == 0) ? gw1 : (m == 1) ? gw2 : (m == 2) ? swl
                         : (m == 3) ? swr : (m == 4) ? (swl + 16384) : (swr + 16384);
        wt[m * 16384 + n * 128 + k] = f2b(src[k * 128 + n]);
    } else {
        int e = (b - CONVX_BLOCKS - WCONV_BLOCKS) * 256 + t;
        if (e < N_EDGES) atomicAdd(&deg[dst[e]], 1);
    }
}

// ---------------------------------------------------------------------------
// alloc (per-block scan + atomic base) + gstart (binary search), fused
// ---------------------------------------------------------------------------
#define ALLOC_BLOCKS 196
__global__ __launch_bounds__(256) void alloc_kernel(int* __restrict__ cursor,
                                                    int* __restrict__ row_beg,
                                                    float* __restrict__ inv_deg,
                                                    int* __restrict__ total,
                                                    const int* __restrict__ batch,
                                                    int* __restrict__ gstart) {
    if (blockIdx.x >= ALLOC_BLOCKS) {
        int g = (blockIdx.x - ALLOC_BLOCKS) * 256 + threadIdx.x;
        if (g > N_GRAPHS) return;
        int lo = 0, hi = N_NODES;
        while (lo < hi) {
            int mid = (lo + hi) >> 1;
            if (batch[mid] < g) lo = mid + 1; else hi = mid;
        }
        gstart[g] = lo;
        return;
    }
    __shared__ int tmp[256];
    __shared__ int base;
    int i = blockIdx.x * 256 + threadIdx.x;
    int d = (i < N_NODES) ? cursor[i] : 0;
    tmp[threadIdx.x] = d;
    __syncthreads();
#pragma unroll
    for (int off = 1; off < 256; off <<= 1) {
        int v = (threadIdx.x >= off) ? tmp[threadIdx.x - off] : 0;
        __syncthreads();
        tmp[threadIdx.x] += v;
        __syncthreads();
    }
    if (threadIdx.x == 255) base = atomicAdd(total, tmp[255]);
    __syncthreads();
    if (i < N_NODES) {
        int b = base + tmp[threadIdx.x] - d;
        row_beg[i] = b;
        cursor[i] = b;
        inv_deg[i] = 1.0f / fmaxf((float)d, 1.0f);
    }
}

__global__ void csr_fill_kernel(const int* __restrict__ src, const int* __restrict__ dst,
                                int* __restrict__ cursor, int* __restrict__ csr_src, int nE) {
    int e = blockIdx.x * blockDim.x + threadIdx.x;
    if (e < nE) {
        int pos = atomicAdd(&cursor[dst[e]], 1);
        csr_src[pos] = src[e];
    }
}

// ---------------------------------------------------------------------------
// aggregate: agg[i] = (sum_e act(feat[src[e]])) * (MEAN? inv_deg : 1)
// AFF: act(v) = relu(v*c+s) with affine computed in-kernel from stats
// HACT: also write hact[i] = act(feat[i])
// 32 lanes/node, ushort4 loads, 4x edge unroll
// ---------------------------------------------------------------------------
template<bool AFF, bool MEAN, bool HACT>
__global__ __launch_bounds__(256) void aggregate_kernel(
    const unsigned short* __restrict__ feat,
    const int* __restrict__ row_beg, const int* __restrict__ row_end,
    const int* __restrict__ csr_src,
    const float* __restrict__ stats, const float* __restrict__ gamma,
    const float* __restrict__ beta, const float* __restrict__ inv_deg,
    unsigned short* __restrict__ agg, unsigned short* __restrict__ hact, int n)
{
    int gid = blockIdx.x * blockDim.x + threadIdx.x;
    int node = gid >> 5;
    int lane = gid & 31;
    if (node >= n) return;
    int c0 = lane * 4;

    float cc0 = 1.f, cc1 = 1.f, cc2 = 1.f, cc3 = 1.f;
    float ss0 = 0.f, ss1 = 0.f, ss2 = 0.f, ss3 = 0.f;
    if (AFF) {
#pragma unroll
        for (int j = 0; j < 4; j++) {
            int col = c0 + j;
            float mu = stats[col] * INV_N;
            float var = stats[128 + col] * INV_N - mu * mu;
            float rs = rsqrtf(var + BN_EPS);
            float c = gamma[col] * rs;
            float s = beta[col] - mu * c;
            if (j == 0) { cc0 = c; ss0 = s; }
            if (j == 1) { cc1 = c; ss1 = s; }
            if (j == 2) { cc2 = c; ss2 = s; }
            if (j == 3) { cc3 = c; ss3 = s; }
        }
    }

#define ACT_ACC(v)                                              \
    {                                                           \
        float t0 = b2f(v.x), t1 = b2f(v.y), t2 = b2f(v.z), t3 = b2f(v.w); \
        if (AFF) {                                              \
            t0 = fmaxf(t0 * cc0 + ss0, 0.f);                    \
            t1 = fmaxf(t1 * cc1 + ss1, 0.f);                    \
            t2 = fmaxf(t2 * cc2 + ss2, 0.f);                    \
            t3 = fmaxf(t3 * cc3 + ss3, 0.f);                    \
        }                                                       \
        a0 += t0; a1 += t1; a2 += t2; a3 += t3;                 \
    }

    int beg = row_beg[node];
    int end = row_end[node];
    float a0 = 0.f, a1 = 0.f, a2 = 0.f, a3 = 0.f;
    int e = beg;
    for (; e + 3 < end; e += 4) {
        int s0 = csr_src[e];
        int s1 = csr_src[e + 1];
        int s2 = csr_src[e + 2];
        int s3 = csr_src[e + 3];
        ushort4 v0 = *(const ushort4*)(feat + (size_t)s0 * 128 + c0);
        ushort4 v1 = *(const ushort4*)(feat + (size_t)s1 * 128 + c0);
        ushort4 v2 = *(const ushort4*)(feat + (size_t)s2 * 128 + c0);
        ushort4 v3 = *(const ushort4*)(feat + (size_t)s3 * 128 + c0);
        ACT_ACC(v0); ACT_ACC(v1); ACT_ACC(v2); ACT_ACC(v3);
    }
    for (; e < end; e++) {
        int s0 = csr_src[e];
        ushort4 v0 = *(const ushort4*)(feat + (size_t)s0 * 128 + c0);
        ACT_ACC(v0);
    }
#undef ACT_ACC

    if (MEAN) {
        float s = inv_deg[node];
        a0 *= s; a1 *= s; a2 *= s; a3 *= s;
    }
    ushort4 o;
    o.x = f2b(a0); o.y = f2b(a1); o.z = f2b(a2); o.w = f2b(a3);
    *(ushort4*)(agg + (size_t)node * 128 + c0) = o;

    if (HACT) {
        ushort4 v = *(const ushort4*)(feat + (size_t)node * 128 + c0);
        ushort4 h;
        h.x = f2b(fmaxf(b2f(v.x) * cc0 + ss0, 0.f));
        h.y = f2b(fmaxf(b2f(v.y) * cc1 + ss1, 0.f));
        h.z = f2b(fmaxf(b2f(v.z) * cc2 + ss2, 0.f));
        h.w = f2b(fmaxf(b2f(v.w) * cc3 + ss3, 0.f));
        *(ushort4*)(hact + (size_t)node * 128 + c0) = h;
    }
}

// ---------------------------------------------------------------------------
// Single-matrix W-stationary MFMA GEMM (swapped operands, bf16 out).
// ADD2: A = bf16(b2f(A1)+b2f(A2));  RELU: relu before store;
// STATS: fp32 col sum/sumsq (pre-relu values; only used with RELU=false).
// ---------------------------------------------------------------------------
template<bool ADD2, bool RELU, bool STATS>
__global__ __launch_bounds__(256) void gemm_single_kernel(
    const unsigned short* __restrict__ A1, const unsigned short* __restrict__ A2,
    const unsigned short* __restrict__ Wt, const float* __restrict__ bias,
    float* __restrict__ stats, unsigned short* __restrict__ Cb,
    int M, int ntiles)
{
    __shared__ float red[2][128];

    const int t = threadIdx.x;
    const int wave = t >> 6;
    const int lane = t & 63;
    const int colhalf = wave & 1;
    const int rowpair = wave >> 1;
    const int m16 = lane & 15;
    const int quad = lane >> 4;
    const int k0 = quad * 8;
    const int colbase = colhalf * 64;

    const bf16x8 zero8 = {0, 0, 0, 0, 0, 0, 0, 0};

    bf16x8 wf[4][4];
#pragma unroll
    for (int ct = 0; ct < 4; ct++) {
        int col = colbase + ct * 16 + m16;
#pragma unroll
        for (int kc = 0; kc < 4; kc++)
            wf[ct][kc] = *(const bf16x8*)(Wt + (size_t)col * 128 + kc * 32 + k0);
    }
    f32x4 bs[4];
#pragma unroll
    for (int ct = 0; ct < 4; ct++)
        bs[ct] = *(const f32x4*)(bias + colbase + ct * 16 + quad * 4);

    float psum[4][4], psq[4][4];
    if (STATS) {
#pragma unroll
        for (int ct = 0; ct < 4; ct++)
#pragma unroll
            for (int r = 0; r < 4; r++) { psum[ct][r] = 0.f; psq[ct][r] = 0.f; }
    }

    bf16x8 a1[4], a2[4], a1n[4], a2n[4];

    int tile = blockIdx.x;
    if (tile < ntiles) {
        int arow = tile * 32 + rowpair * 16 + m16;
        bool aok = arow < M;
#pragma unroll
        for (int kc = 0; kc < 4; kc++) {
            a1[kc] = aok ? *(const bf16x8*)(A1 + (size_t)arow * 128 + kc * 32 + k0) : zero8;
            if (ADD2)
                a2[kc] = aok ? *(const bf16x8*)(A2 + (size_t)arow * 128 + kc * 32 + k0) : zero8;
        }
    }

    for (; tile < ntiles; tile += gridDim.x) {
        int nt = tile + gridDim.x;
        if (nt < ntiles) {
            int arow = nt * 32 + rowpair * 16 + m16;
            bool aok = arow < M;
#pragma unroll
            for (int kc = 0; kc < 4; kc++) {
                a1n[kc] = aok ? *(const bf16x8*)(A1 + (size_t)arow * 128 + kc * 32 + k0) : zero8;
                if (ADD2)
                    a2n[kc] = aok ? *(const bf16x8*)(A2 + (size_t)arow * 128 + kc * 32 + k0) : zero8;
            }
        }

        f32x4 acc[4];
#pragma unroll
        for (int ct = 0; ct < 4; ct++) acc[ct] = (f32x4){0.f, 0.f, 0.f, 0.f};
#pragma unroll
        for (int kc = 0; kc < 4; kc++) {
            bf16x8 a = a1[kc];
            if (ADD2) {
                bf16x8 r;
#pragma unroll
                for (int i = 0; i < 8; i++)
                    r[i] = (short)f2b(b2f((unsigned short)a1[kc][i]) + b2f((unsigned short)a2[kc][i]));
                a = r;
            }
#pragma unroll
            for (int ct = 0; ct < 4; ct++)
                acc[ct] = __builtin_amdgcn_mfma_f32_16x16x32_bf16(wf[ct][kc], a, acc[ct], 0, 0, 0);
        }

        int orow = tile * 32 + rowpair * 16 + m16;
        if (orow < M) {
#pragma unroll
            for (int ct = 0; ct < 4; ct++) {
                f32x4 v = acc[ct] + bs[ct];
                int col = colbase + ct * 16 + quad * 4;
                if (STATS) {
#pragma unroll
                    for (int r = 0; r < 4; r++) { psum[ct][r] += v[r]; psq[ct][r] += v[r] * v[r]; }
                }
                ushort4 o;
                if (RELU) {
                    o.x = f2b(fmaxf(v[0], 0.f)); o.y = f2b(fmaxf(v[1], 0.f));
                    o.z = f2b(fmaxf(v[2], 0.f)); o.w = f2b(fmaxf(v[3], 0.f));
                } else {
                    o.x = f2b(v[0]); o.y = f2b(v[1]); o.z = f2b(v[2]); o.w = f2b(v[3]);
                }
                *(ushort4*)(Cb + (size_t)orow * 128 + col) = o;
            }
        }

        if (nt < ntiles) {
            a1[0] = a1n[0]; a1[1] = a1n[1]; a1[2] = a1n[2]; a1[3] = a1n[3];
            if (ADD2) { a2[0] = a2n[0]; a2[1] = a2n[1]; a2[2] = a2n[2]; a2[3] = a2n[3]; }
        }
    }

    if (STATS) {
#pragma unroll
        for (int ct = 0; ct < 4; ct++)
#pragma unroll
            for (int r = 0; r < 4; r++) {
#pragma unroll
                for (int mask = 1; mask <= 8; mask <<= 1) {
                    psum[ct][r] += __shfl_xor(psum[ct][r], mask, 64);
                    psq[ct][r]  += __shfl_xor(psq[ct][r], mask, 64);
                }
            }
        if (m16 == 0) {
#pragma unroll
            for (int ct = 0; ct < 4; ct++)
#pragma unroll
                for (int r = 0; r < 4; r++)
                    red[rowpair][colbase + ct * 16 + quad * 4 + r] = psum[ct][r];
        }
        __syncthreads();
        if (t < 128) atomicAdd(&stats[t], red[0][t] + red[1][t]);
        __syncthreads();
        if (m16 == 0) {
#pragma unroll
            for (int ct = 0; ct < 4; ct++)
#pragma unroll
                for (int r = 0; r < 4; r++)
                    red[rowpair][colbase + ct * 16 + quad * 4 + r] = psq[ct][r];
        }
        __syncthreads();
        if (t < 128) atomicAdd(&stats[128 + t], red[0][t] + red[1][t]);
    }
}

// ---------------------------------------------------------------------------
// Dual-matrix GEMM (SAGE): Cb = bf16(A1@W1 + A2@W2 + bias), stats fp32.
// Wave = 16 rows x 32 cols; A shared across waves (L1 broadcast).
// ---------------------------------------------------------------------------
__global__ __launch_bounds__(256) void gemm_dual_kernel(
    const unsigned short* __restrict__ A1, const unsigned short* __restrict__ A2,
    const unsigned short* __restrict__ W1t, const unsigned short* __restrict__ W2t,
    const float* __restrict__ bias, float* __restrict__ stats,
    unsigned short* __restrict__ Cb, int M, int ntiles)
{
    __shared__ float red[128];

    const int t = threadIdx.x;
    const int wave = t >> 6;
    const int lane = t & 63;
    const int m16 = lane & 15;
    const int quad = lane >> 4;
    const int k0 = quad * 8;
    const int colbase = wave * 32;

    const bf16x8 zero8 = {0, 0, 0, 0, 0, 0, 0, 0};

    bf16x8 w1f[2][4], w2f[2][4];
#pragma unroll
    for (int ct = 0; ct < 2; ct++) {
        int col = colbase + ct * 16 + m16;
#pragma unroll
        for (int kc = 0; kc < 4; kc++) {
            w1f[ct][kc] = *(const bf16x8*)(W1t + (size_t)col * 128 + kc * 32 + k0);
            w2f[ct][kc] = *(const bf16x8*)(W2t + (size_t)col * 128 + kc * 32 + k0);
        }
    }
    f32x4 bs[2];
#pragma unroll
    for (int ct = 0; ct < 2; ct++)
        bs[ct] = *(const f32x4*)(bias + colbase + ct * 16 + quad * 4);

    float psum[2][4], psq[2][4];
#pragma unroll
    for (int ct = 0; ct < 2; ct++)
#pragma unroll
        for (int r = 0; r < 4; r++) { psum[ct][r] = 0.f; psq[ct][r] = 0.f; }

    bf16x8 a1[4], a2[4], a1n[4], a2n[4];

    int tile = blockIdx.x;
    if (tile < ntiles) {
        int arow = tile * 16 + m16;
        bool aok = arow < M;
#pragma unroll
        for (int kc = 0; kc < 4; kc++) {
            a1[kc] = aok ? *(const bf16x8*)(A1 + (size_t)arow * 128 + kc * 32 + k0) : zero8;
            a2[kc] = aok ? *(const bf16x8*)(A2 + (size_t)arow * 128 + kc * 32 + k0) : zero8;
        }
    }

    for (; tile < ntiles; tile += gridDim.x) {
        int nt = tile + gridDim.x;
        if (nt < ntiles) {
            int arow = nt * 16 + m16;
            bool aok = arow < M;
#pragma unroll
            for (int kc = 0; kc < 4; kc++) {
                a1n[kc] = aok ? *(const bf16x8*)(A1 + (size_t)arow * 128 + kc * 32 + k0) : zero8;
                a2n[kc] = aok ? *(const bf16x8*)(A2 + (size_t)arow * 128 + kc * 32 + k0) : zero8;
            }
        }

        f32x4 acc[2];
        acc[0] = (f32x4){0.f, 0.f, 0.f, 0.f};
        acc[1] = (f32x4){0.f, 0.f, 0.f, 0.f};
#pragma unroll
        for (int kc = 0; kc < 4; kc++) {
#pragma unroll
            for (int ct = 0; ct < 2; ct++) {
                acc[ct] = __builtin_amdgcn_mfma_f32_16x16x32_bf16(w1f[ct][kc], a1[kc], acc[ct], 0, 0, 0);
                acc[ct] = __builtin_amdgcn_mfma_f32_16x16x32_bf16(w2f[ct][kc], a2[kc], acc[ct], 0, 0, 0);
            }
        }

        int orow = tile * 16 + m16;
        if (orow < M) {
#pragma unroll
            for (int ct = 0; ct < 2; ct++) {
                f32x4 v = acc[ct] + bs[ct];
                int col = colbase + ct * 16 + quad * 4;
#pragma unroll
                for (int r = 0; r < 4; r++) { psum[ct][r] += v[r]; psq[ct][r] += v[r] * v[r]; }
                ushort4 o;
                o.x = f2b(v[0]); o.y = f2b(v[1]); o.z = f2b(v[2]); o.w = f2b(v[3]);
                *(ushort4*)(Cb + (size_t)orow * 128 + col) = o;
            }
        }

        if (nt < ntiles) {
            a1[0] = a1n[0]; a1[1] = a1n[1]; a1[2] = a1n[2]; a1[3] = a1n[3];
            a2[0] = a2n[0]; a2[1] = a2n[1]; a2[2] = a2n[2]; a2[3] = a2n[3];
        }
    }

#pragma unroll
    for (int ct = 0; ct < 2; ct++)
#pragma unroll
        for (int r = 0; r < 4; r++) {
#pragma unroll
            for (int mask = 1; mask <= 8; mask <<= 1) {
                psum[ct][r] += __shfl_xor(psum[ct][r], mask, 64);
                psq[ct][r]  += __shfl_xor(psq[ct][r], mask, 64);
            }
        }
    if (m16 == 0) {
#pragma unroll
        for (int ct = 0; ct < 2; ct++)
#pragma unroll
            for (int r = 0; r < 4; r++)
                red[colbase + ct * 16 + quad * 4 + r] = psum[ct][r];
    }
    __syncthreads();
    if (t < 128) atomicAdd(&stats[t], red[t]);
    __syncthreads();
    if (m16 == 0) {
#pragma unroll
        for (int ct = 0; ct < 2; ct++)
#pragma unroll
            for (int r = 0; r < 4; r++)
                red[colbase + ct * 16 + quad * 4 + r] = psq[ct][r];
    }
    __syncthreads();
    if (t < 128) atomicAdd(&stats[128 + t], red[t]);
}

// ---------------------------------------------------------------------------
// global mean pool: BN affine computed in-kernel from stats, relu, mean
// ---------------------------------------------------------------------------
__global__ __launch_bounds__(128) void pool_mean_kernel(const unsigned short* __restrict__ h,
                                                        const int* __restrict__ gstart,
                                                        const float* __restrict__ stats,
                                                        const float* __restrict__ gamma,
                                                        const float* __restrict__ beta,
                                                        float* __restrict__ out) {
    int g = blockIdx.x;
    int col = threadIdx.x;
    float mu = stats[col] * INV_N;
    float var = stats[128 + col] * INV_N - mu * mu;
    float rs = rsqrtf(var + BN_EPS);
    float c = gamma[col] * rs;
    float b = beta[col] - mu * c;
    int beg = gstart[g];
    int end = gstart[g + 1];
    float s = 0.f;
    for (int i = beg; i < end; i++)
        s += fmaxf(b2f(h[(size_t)i * 128 + col]) * c + b, 0.f);
    float cnt = fmaxf((float)(end - beg), 1.0f);
    out[(size_t)g * 128 + col] = s / cnt;
}

// ---------------------------------------------------------------------------
extern "C" void kernel_launch(void* const* d_in, const int* in_sizes, int n_in,
                              void* d_out, int out_size, void* d_ws, size_t ws_size,
                              hipStream_t stream) {
    const float* x    = (const float*)d_in[0];
    const int*   ei   = (const int*)d_in[1];
    const int*   src  = ei;
    const int*   dst  = ei + N_EDGES;
    const int*   batch = (const int*)d_in[2];
    const float* gw1  = (const float*)d_in[3];
    const float* gb1  = (const float*)d_in[4];
    const float* gw2  = (const float*)d_in[5];
    const float* gb2  = (const float*)d_in[6];
    const float* swl  = (const float*)d_in[7];
    const float* sbl  = (const float*)d_in[8];
    const float* swr  = (const float*)d_in[9];
    const float* bng  = (const float*)d_in[10];
    const float* bnb  = (const float*)d_in[11];
    float* out = (float*)d_out;

    // workspace layout (float units; all bf16 buffers 16B-aligned)
    float* ws = (float*)d_ws;
    unsigned short* x16    = (unsigned short*)(ws + 0);         // 6.4M u16 (also T1)
    unsigned short* agg16  = (unsigned short*)(ws + 3200000);
    unsigned short* hact16 = (unsigned short*)(ws + 6400000);
    unsigned short* hpre16 = (unsigned short*)(ws + 9600000);
    unsigned short* wt     = (unsigned short*)(ws + 12800000);  // 6*16384 u16
    float*          inv_deg= ws + 12850000;                     // 50000
    float*          stats  = ws + 12900000;                     // 3*256
    int*            row_beg= (int*)(ws + 12901000);             // 50000
    int*            cursor = (int*)(ws + 12951000);             // 50000 + total at [50000]
    int*            total  = cursor + 50000;
    int*            csr_src= (int*)(ws + 13100000);             // 600000
    int*            gstart = (int*)(ws + 13701000);             // 513

    const int elem_blocks = (N_NODES * 32 + 255) / 256;         // 6250
    const int ntiles32 = (N_NODES + 31) / 32;                   // 1563
    const int ntiles16 = (N_NODES + 15) / 16;                   // 3125
    const int ggrid = 512;

    // ---- init ----
    hipMemsetAsync(cursor, 0, (N_NODES + 1) * sizeof(int), stream);
    hipMemsetAsync(stats, 0, 3 * 256 * sizeof(float), stream);

    // ---- prep: x->bf16, weights->bf16^T, degree count ----
    prep_kernel<<<CONVX_BLOCKS + WCONV_BLOCKS + DEG_BLOCKS, 256, 0, stream>>>(
        x, gw1, gw2, swl, swr, dst, x16, wt, cursor);

    // ---- CSR ----
    alloc_kernel<<<ALLOC_BLOCKS + 3, 256, 0, stream>>>(cursor, row_beg, inv_deg, total, batch, gstart);
    csr_fill_kernel<<<(N_EDGES + 255) / 256, 256, 0, stream>>>(src, dst, cursor, csr_src, N_EDGES);

    // ---- GIN ----
    aggregate_kernel<false, false, false><<<elem_blocks, 256, 0, stream>>>(
        x16, row_beg, cursor, csr_src, nullptr, nullptr, nullptr, nullptr, agg16, nullptr, N_NODES);
    // T1 = relu((x+agg)@W1 + b1) -> bf16 (in-place over x16: tile rows read-then-write)
    gemm_single_kernel<true, true, false><<<ggrid, 256, 0, stream>>>(
        x16, agg16, wt + 0 * 16384, gb1, nullptr, x16, N_NODES, ntiles32);
    // h0pre = T1@W2 + b2 -> bf16 + stats0
    gemm_single_kernel<false, false, true><<<ggrid, 256, 0, stream>>>(
        x16, nullptr, wt + 1 * 16384, gb2, stats + 0, hpre16, N_NODES, ntiles32);

    // ---- SAGE 0 ----
    aggregate_kernel<true, true, true><<<elem_blocks, 256, 0, stream>>>(
        hpre16, row_beg, cursor, csr_src, stats + 0, bng + 0 * HID, bnb + 0 * HID, inv_deg,
        agg16, hact16, N_NODES);
    gemm_dual_kernel<<<ggrid, 256, 0, stream>>>(
        agg16, hact16, wt + 2 * 16384, wt + 3 * 16384, sbl + 0 * HID, stats + 256, hpre16, N_NODES, ntiles16);

    // ---- SAGE 1 ----
    aggregate_kernel<true, true, true><<<elem_blocks, 256, 0, stream>>>(
        hpre16, row_beg, cursor, csr_src, stats + 256, bng + 1 * HID, bnb + 1 * HID, inv_deg,
        agg16, hact16, N_NODES);
    gemm_dual_kernel<<<ggrid, 256, 0, stream>>>(
        agg16, hact16, wt + 4 * 16384, wt + 5 * 16384, sbl + 1 * HID, stats + 512, hpre16, N_NODES, ntiles16);

    // ---- pool (BN2 affine folded) ----
    pool_mean_kernel<<<N_GRAPHS, 128, 0, stream>>>(
        hpre16, gstart, stats + 512, bng + 2 * HID, bnb + 2 * HID, out);
}

// Round 11
// 362.747 us; speedup vs baseline: 1.5610x; 1.0600x over previous
//
#include <hip/hip_runtime.h>

#define N_NODES 50000
#define N_EDGES 600000
#define HID 128
#define N_GRAPHS 512
#define BN_EPS 1e-5f
#define INV_N (1.0f / 50000.0f)

typedef __attribute__((ext_vector_type(8))) short bf16x8;
typedef __attribute__((ext_vector_type(4))) float f32x4;

__device__ __forceinline__ unsigned short f2b(float f) {
    unsigned u = __float_as_uint(f);
    return (unsigned short)((u + 0x7FFFu + ((u >> 16) & 1u)) >> 16);
}
__device__ __forceinline__ float b2f(unsigned short h) {
    return __uint_as_float(((unsigned)h) << 16);
}

// ---------------------------------------------------------------------------
// prep: convert x -> bf16 | transpose+convert 6 weight mats | degree count
// ---------------------------------------------------------------------------
#define CONVX_BLOCKS 6250
#define WCONV_BLOCKS 384
#define DEG_BLOCKS   2344
__global__ __launch_bounds__(256) void prep_kernel(
    const float* __restrict__ x, const float* __restrict__ gw1, const float* __restrict__ gw2,
    const float* __restrict__ swl, const float* __restrict__ swr, const int* __restrict__ dst,
    unsigned short* __restrict__ x16, unsigned short* __restrict__ wt, int* __restrict__ deg)
{
    int b = blockIdx.x;
    int t = threadIdx.x;
    if (b < CONVX_BLOCKS) {
        int gid = b * 256 + t;
        int i = gid >> 5, l = gid & 31;
        if (i >= N_NODES) return;
        int c0 = l * 4;
        float4 v = *(const float4*)(x + (size_t)i * 128 + c0);
        ushort4 o;
        o.x = f2b(v.x); o.y = f2b(v.y); o.z = f2b(v.z); o.w = f2b(v.w);
        *(ushort4*)(x16 + (size_t)i * 128 + c0) = o;
    } else if (b < CONVX_BLOCKS + WCONV_BLOCKS) {
        int gid = (b - CONVX_BLOCKS) * 256 + t;   // < 6*16384
        int m = gid >> 14;
        int e = gid & 16383;
        int k = e >> 7;
        int n = e & 127;
        const float* src = (m == 0) ? gw1 : (m == 1) ? gw2 : (m == 2) ? swl
                         : (m == 3) ? swr : (m == 4) ? (swl + 16384) : (swr + 16384);
        wt[m * 16384 + n * 128 + k] = f2b(src[k * 128 + n]);
    } else {
        int e = (b - CONVX_BLOCKS - WCONV_BLOCKS) * 256 + t;
        if (e < N_EDGES) atomicAdd(&deg[dst[e]], 1);
    }
}

// ---------------------------------------------------------------------------
// alloc (per-block scan + atomic base) + gstart (binary search), fused
// ---------------------------------------------------------------------------
#define ALLOC_BLOCKS 196
__global__ __launch_bounds__(256) void alloc_kernel(int* __restrict__ cursor,
                                                    int* __restrict__ row_beg,
                                                    float* __restrict__ inv_deg,
                                                    int* __restrict__ total,
                                                    const int* __restrict__ batch,
                                                    int* __restrict__ gstart) {
    if (blockIdx.x >= ALLOC_BLOCKS) {
        int g = (blockIdx.x - ALLOC_BLOCKS) * 256 + threadIdx.x;
        if (g > N_GRAPHS) return;
        int lo = 0, hi = N_NODES;
        while (lo < hi) {
            int mid = (lo + hi) >> 1;
            if (batch[mid] < g) lo = mid + 1; else hi = mid;
        }
        gstart[g] = lo;
        return;
    }
    __shared__ int tmp[256];
    __shared__ int base;
    int i = blockIdx.x * 256 + threadIdx.x;
    int d = (i < N_NODES) ? cursor[i] : 0;
    tmp[threadIdx.x] = d;
    __syncthreads();
#pragma unroll
    for (int off = 1; off < 256; off <<= 1) {
        int v = (threadIdx.x >= off) ? tmp[threadIdx.x - off] : 0;
        __syncthreads();
        tmp[threadIdx.x] += v;
        __syncthreads();
    }
    if (threadIdx.x == 255) base = atomicAdd(total, tmp[255]);
    __syncthreads();
    if (i < N_NODES) {
        int b = base + tmp[threadIdx.x] - d;
        row_beg[i] = b;
        cursor[i] = b;
        inv_deg[i] = 1.0f / fmaxf((float)d, 1.0f);
    }
}

__global__ void csr_fill_kernel(const int* __restrict__ src, const int* __restrict__ dst,
                                int* __restrict__ cursor, int* __restrict__ csr_src, int nE) {
    int e = blockIdx.x * blockDim.x + threadIdx.x;
    if (e < nE) {
        int pos = atomicAdd(&cursor[dst[e]], 1);
        csr_src[pos] = src[e];
    }
}

// ---------------------------------------------------------------------------
// aggregate: agg[i] = (sum_e act(feat[src[e]])) * (MEAN? inv_deg : 1)
// AFF: act(v) = relu(v*c+s), affine computed in-kernel from stats
// HACT: also write hact[i] = act(feat[i])
// 16 lanes per node, bf16x8 (16B) loads, 4x edge unroll
// ---------------------------------------------------------------------------
template<bool AFF, bool MEAN, bool HACT>
__global__ __launch_bounds__(256) void aggregate_kernel(
    const unsigned short* __restrict__ feat,
    const int* __restrict__ row_beg, const int* __restrict__ row_end,
    const int* __restrict__ csr_src,
    const float* __restrict__ stats, const float* __restrict__ gamma,
    const float* __restrict__ beta, const float* __restrict__ inv_deg,
    unsigned short* __restrict__ agg, unsigned short* __restrict__ hact, int n)
{
    int gid = blockIdx.x * blockDim.x + threadIdx.x;
    int node = gid >> 4;
    int lane = gid & 15;
    if (node >= n) return;
    int c0 = lane * 8;

    float cc[8], ss[8];
    if (AFF) {
#pragma unroll
        for (int j = 0; j < 8; j++) {
            int col = c0 + j;
            float mu = stats[col] * INV_N;
            float var = stats[128 + col] * INV_N - mu * mu;
            float rs = rsqrtf(var + BN_EPS);
            float c = gamma[col] * rs;
            cc[j] = c;
            ss[j] = beta[col] - mu * c;
        }
    }

    float a[8];
#pragma unroll
    for (int j = 0; j < 8; j++) a[j] = 0.f;

    int beg = row_beg[node];
    int end = row_end[node];
    int e = beg;
    for (; e + 3 < end; e += 4) {
        int s0 = csr_src[e];
        int s1 = csr_src[e + 1];
        int s2 = csr_src[e + 2];
        int s3 = csr_src[e + 3];
        bf16x8 v0 = *(const bf16x8*)(feat + (size_t)s0 * 128 + c0);
        bf16x8 v1 = *(const bf16x8*)(feat + (size_t)s1 * 128 + c0);
        bf16x8 v2 = *(const bf16x8*)(feat + (size_t)s2 * 128 + c0);
        bf16x8 v3 = *(const bf16x8*)(feat + (size_t)s3 * 128 + c0);
#pragma unroll
        for (int j = 0; j < 8; j++) {
            float t0 = b2f((unsigned short)v0[j]);
            float t1 = b2f((unsigned short)v1[j]);
            float t2 = b2f((unsigned short)v2[j]);
            float t3 = b2f((unsigned short)v3[j]);
            if (AFF) {
                t0 = fmaxf(t0 * cc[j] + ss[j], 0.f);
                t1 = fmaxf(t1 * cc[j] + ss[j], 0.f);
                t2 = fmaxf(t2 * cc[j] + ss[j], 0.f);
                t3 = fmaxf(t3 * cc[j] + ss[j], 0.f);
            }
            a[j] += (t0 + t1) + (t2 + t3);
        }
    }
    for (; e < end; e++) {
        int s0 = csr_src[e];
        bf16x8 v0 = *(const bf16x8*)(feat + (size_t)s0 * 128 + c0);
#pragma unroll
        for (int j = 0; j < 8; j++) {
            float t0 = b2f((unsigned short)v0[j]);
            if (AFF) t0 = fmaxf(t0 * cc[j] + ss[j], 0.f);
            a[j] += t0;
        }
    }

    if (MEAN) {
        float s = inv_deg[node];
#pragma unroll
        for (int j = 0; j < 8; j++) a[j] *= s;
    }
    bf16x8 o;
#pragma unroll
    for (int j = 0; j < 8; j++) o[j] = (short)f2b(a[j]);
    *(bf16x8*)(agg + (size_t)node * 128 + c0) = o;

    if (HACT) {
        bf16x8 v = *(const bf16x8*)(feat + (size_t)node * 128 + c0);
        bf16x8 h;
#pragma unroll
        for (int j = 0; j < 8; j++)
            h[j] = (short)f2b(fmaxf(b2f((unsigned short)v[j]) * cc[j] + ss[j], 0.f));
        *(bf16x8*)(hact + (size_t)node * 128 + c0) = h;
    }
}

// ---------------------------------------------------------------------------
// Fused GIN GEMM: Cb = bf16( relu((X+AGG)@W1 + b1) @ W2 + b2 ), stats fp32.
// Both W1,W2 register-stationary (128 VGPR); T1 round-trips through a 32x136
// LDS tile (C-layout -> B-operand layout). Swapped-operand MFMA:
// thread owns node row = m16, weight cols = colbase + ct*16 + quad*4 + r.
// ---------------------------------------------------------------------------
__global__ __launch_bounds__(256, 2) void gemm_gin_kernel(
    const unsigned short* __restrict__ X, const unsigned short* __restrict__ AGG,
    const unsigned short* __restrict__ W1t, const unsigned short* __restrict__ W2t,
    const float* __restrict__ b1, const float* __restrict__ b2,
    float* __restrict__ stats, unsigned short* __restrict__ Cb,
    int M, int ntiles)
{
    __shared__ unsigned short t1[32][136];
    __shared__ float red[2][128];

    const int t = threadIdx.x;
    const int wave = t >> 6;
    const int lane = t & 63;
    const int colhalf = wave & 1;
    const int rowpair = wave >> 1;
    const int m16 = lane & 15;
    const int quad = lane >> 4;
    const int k0 = quad * 8;
    const int colbase = colhalf * 64;
    const int lrow = rowpair * 16 + m16;

    const bf16x8 zero8 = {0, 0, 0, 0, 0, 0, 0, 0};

    bf16x8 w1f[4][4], w2f[4][4];
#pragma unroll
    for (int ct = 0; ct < 4; ct++) {
        int col = colbase + ct * 16 + m16;
#pragma unroll
        for (int kc = 0; kc < 4; kc++) {
            w1f[ct][kc] = *(const bf16x8*)(W1t + (size_t)col * 128 + kc * 32 + k0);
            w2f[ct][kc] = *(const bf16x8*)(W2t + (size_t)col * 128 + kc * 32 + k0);
        }
    }
    f32x4 bs1[4], bs2[4];
#pragma unroll
    for (int ct = 0; ct < 4; ct++) {
        bs1[ct] = *(const f32x4*)(b1 + colbase + ct * 16 + quad * 4);
        bs2[ct] = *(const f32x4*)(b2 + colbase + ct * 16 + quad * 4);
    }

    float psum[4][4], psq[4][4];
#pragma unroll
    for (int ct = 0; ct < 4; ct++)
#pragma unroll
        for (int r = 0; r < 4; r++) { psum[ct][r] = 0.f; psq[ct][r] = 0.f; }

    for (int tile = blockIdx.x; tile < ntiles; tile += gridDim.x) {
        int arow = tile * 32 + rowpair * 16 + m16;
        bool aok = arow < M;

        // A = bf16(x + agg)
        bf16x8 a[4];
#pragma unroll
        for (int kc = 0; kc < 4; kc++) {
            if (aok) {
                bf16x8 vx = *(const bf16x8*)(X + (size_t)arow * 128 + kc * 32 + k0);
                bf16x8 vg = *(const bf16x8*)(AGG + (size_t)arow * 128 + kc * 32 + k0);
                bf16x8 r;
#pragma unroll
                for (int i = 0; i < 8; i++)
                    r[i] = (short)f2b(b2f((unsigned short)vx[i]) + b2f((unsigned short)vg[i]));
                a[kc] = r;
            } else {
                a[kc] = zero8;
            }
        }

        // phase 1
        f32x4 acc[4];
#pragma unroll
        for (int ct = 0; ct < 4; ct++) acc[ct] = (f32x4){0.f, 0.f, 0.f, 0.f};
#pragma unroll
        for (int kc = 0; kc < 4; kc++)
#pragma unroll
            for (int ct = 0; ct < 4; ct++)
                acc[ct] = __builtin_amdgcn_mfma_f32_16x16x32_bf16(w1f[ct][kc], a[kc], acc[ct], 0, 0, 0);

        // T1 = relu(acc + b1) -> LDS
        __syncthreads();   // previous tile's t1 reads done
#pragma unroll
        for (int ct = 0; ct < 4; ct++) {
            f32x4 v = acc[ct] + bs1[ct];
            ushort4 o;
            o.x = f2b(fmaxf(v[0], 0.f));
            o.y = f2b(fmaxf(v[1], 0.f));
            o.z = f2b(fmaxf(v[2], 0.f));
            o.w = f2b(fmaxf(v[3], 0.f));
            *(ushort4*)&t1[lrow][colbase + ct * 16 + quad * 4] = o;
        }
        __syncthreads();

        // phase 2: A-frags from LDS
        bf16x8 ta[4];
#pragma unroll
        for (int kc = 0; kc < 4; kc++)
            ta[kc] = *(const bf16x8*)&t1[lrow][kc * 32 + k0];

        f32x4 acc2[4];
#pragma unroll
        for (int ct = 0; ct < 4; ct++) acc2[ct] = (f32x4){0.f, 0.f, 0.f, 0.f};
#pragma unroll
        for (int kc = 0; kc < 4; kc++)
#pragma unroll
            for (int ct = 0; ct < 4; ct++)
                acc2[ct] = __builtin_amdgcn_mfma_f32_16x16x32_bf16(w2f[ct][kc], ta[kc], acc2[ct], 0, 0, 0);

        int orow = arow;
        if (orow < M) {
#pragma unroll
            for (int ct = 0; ct < 4; ct++) {
                f32x4 v = acc2[ct] + bs2[ct];
                int col = colbase + ct * 16 + quad * 4;
#pragma unroll
                for (int r = 0; r < 4; r++) { psum[ct][r] += v[r]; psq[ct][r] += v[r] * v[r]; }
                ushort4 o;
                o.x = f2b(v[0]); o.y = f2b(v[1]); o.z = f2b(v[2]); o.w = f2b(v[3]);
                *(ushort4*)(Cb + (size_t)orow * 128 + col) = o;
            }
        }
    }

    // stats flush
#pragma unroll
    for (int ct = 0; ct < 4; ct++)
#pragma unroll
        for (int r = 0; r < 4; r++) {
#pragma unroll
            for (int mask = 1; mask <= 8; mask <<= 1) {
                psum[ct][r] += __shfl_xor(psum[ct][r], mask, 64);
                psq[ct][r]  += __shfl_xor(psq[ct][r], mask, 64);
            }
        }
    __syncthreads();
    if (m16 == 0) {
#pragma unroll
        for (int ct = 0; ct < 4; ct++)
#pragma unroll
            for (int r = 0; r < 4; r++)
                red[rowpair][colbase + ct * 16 + quad * 4 + r] = psum[ct][r];
    }
    __syncthreads();
    if (t < 128) atomicAdd(&stats[t], red[0][t] + red[1][t]);
    __syncthreads();
    if (m16 == 0) {
#pragma unroll
        for (int ct = 0; ct < 4; ct++)
#pragma unroll
            for (int r = 0; r < 4; r++)
                red[rowpair][colbase + ct * 16 + quad * 4 + r] = psq[ct][r];
    }
    __syncthreads();
    if (t < 128) atomicAdd(&stats[128 + t], red[0][t] + red[1][t]);
}

// ---------------------------------------------------------------------------
// Dual-matrix GEMM (SAGE): Cb = bf16(A1@W1 + A2@W2 + bias), stats fp32.
// ---------------------------------------------------------------------------
__global__ __launch_bounds__(256) void gemm_dual_kernel(
    const unsigned short* __restrict__ A1, const unsigned short* __restrict__ A2,
    const unsigned short* __restrict__ W1t, const unsigned short* __restrict__ W2t,
    const float* __restrict__ bias, float* __restrict__ stats,
    unsigned short* __restrict__ Cb, int M, int ntiles)
{
    __shared__ float red[128];

    const int t = threadIdx.x;
    const int wave = t >> 6;
    const int lane = t & 63;
    const int m16 = lane & 15;
    const int quad = lane >> 4;
    const int k0 = quad * 8;
    const int colbase = wave * 32;

    const bf16x8 zero8 = {0, 0, 0, 0, 0, 0, 0, 0};

    bf16x8 w1f[2][4], w2f[2][4];
#pragma unroll
    for (int ct = 0; ct < 2; ct++) {
        int col = colbase + ct * 16 + m16;
#pragma unroll
        for (int kc = 0; kc < 4; kc++) {
            w1f[ct][kc] = *(const bf16x8*)(W1t + (size_t)col * 128 + kc * 32 + k0);
            w2f[ct][kc] = *(const bf16x8*)(W2t + (size_t)col * 128 + kc * 32 + k0);
        }
    }
    f32x4 bs[2];
#pragma unroll
    for (int ct = 0; ct < 2; ct++)
        bs[ct] = *(const f32x4*)(bias + colbase + ct * 16 + quad * 4);

    float psum[2][4], psq[2][4];
#pragma unroll
    for (int ct = 0; ct < 2; ct++)
#pragma unroll
        for (int r = 0; r < 4; r++) { psum[ct][r] = 0.f; psq[ct][r] = 0.f; }

    bf16x8 a1[4], a2[4], a1n[4], a2n[4];

    int tile = blockIdx.x;
    if (tile < ntiles) {
        int arow = tile * 16 + m16;
        bool aok = arow < M;
#pragma unroll
        for (int kc = 0; kc < 4; kc++) {
            a1[kc] = aok ? *(const bf16x8*)(A1 + (size_t)arow * 128 + kc * 32 + k0) : zero8;
            a2[kc] = aok ? *(const bf16x8*)(A2 + (size_t)arow * 128 + kc * 32 + k0) : zero8;
        }
    }

    for (; tile < ntiles; tile += gridDim.x) {
        int nt = tile + gridDim.x;
        if (nt < ntiles) {
            int arow = nt * 16 + m16;
            bool aok = arow < M;
#pragma unroll
            for (int kc = 0; kc < 4; kc++) {
                a1n[kc] = aok ? *(const bf16x8*)(A1 + (size_t)arow * 128 + kc * 32 + k0) : zero8;
                a2n[kc] = aok ? *(const bf16x8*)(A2 + (size_t)arow * 128 + kc * 32 + k0) : zero8;
            }
        }

        f32x4 acc[2];
        acc[0] = (f32x4){0.f, 0.f, 0.f, 0.f};
        acc[1] = (f32x4){0.f, 0.f, 0.f, 0.f};
#pragma unroll
        for (int kc = 0; kc < 4; kc++) {
#pragma unroll
            for (int ct = 0; ct < 2; ct++) {
                acc[ct] = __builtin_amdgcn_mfma_f32_16x16x32_bf16(w1f[ct][kc], a1[kc], acc[ct], 0, 0, 0);
                acc[ct] = __builtin_amdgcn_mfma_f32_16x16x32_bf16(w2f[ct][kc], a2[kc], acc[ct], 0, 0, 0);
            }
        }

        int orow = tile * 16 + m16;
        if (orow < M) {
#pragma unroll
            for (int ct = 0; ct < 2; ct++) {
                f32x4 v = acc[ct] + bs[ct];
                int col = colbase + ct * 16 + quad * 4;
#pragma unroll
                for (int r = 0; r < 4; r++) { psum[ct][r] += v[r]; psq[ct][r] += v[r] * v[r]; }
                ushort4 o;
                o.x = f2b(v[0]); o.y = f2b(v[1]); o.z = f2b(v[2]); o.w = f2b(v[3]);
                *(ushort4*)(Cb + (size_t)orow * 128 + col) = o;
            }
        }

        if (nt < ntiles) {
            a1[0] = a1n[0]; a1[1] = a1n[1]; a1[2] = a1n[2]; a1[3] = a1n[3];
            a2[0] = a2n[0]; a2[1] = a2n[1]; a2[2] = a2n[2]; a2[3] = a2n[3];
        }
    }

#pragma unroll
    for (int ct = 0; ct < 2; ct++)
#pragma unroll
        for (int r = 0; r < 4; r++) {
#pragma unroll
            for (int mask = 1; mask <= 8; mask <<= 1) {
                psum[ct][r] += __shfl_xor(psum[ct][r], mask, 64);
                psq[ct][r]  += __shfl_xor(psq[ct][r], mask, 64);
            }
        }
    if (m16 == 0) {
#pragma unroll
        for (int ct = 0; ct < 2; ct++)
#pragma unroll
            for (int r = 0; r < 4; r++)
                red[colbase + ct * 16 + quad * 4 + r] = psum[ct][r];
    }
    __syncthreads();
    if (t < 128) atomicAdd(&stats[t], red[t]);
    __syncthreads();
    if (m16 == 0) {
#pragma unroll
        for (int ct = 0; ct < 2; ct++)
#pragma unroll
            for (int r = 0; r < 4; r++)
                red[colbase + ct * 16 + quad * 4 + r] = psq[ct][r];
    }
    __syncthreads();
    if (t < 128) atomicAdd(&stats[128 + t], red[t]);
}

// ---------------------------------------------------------------------------
// global mean pool: BN affine from stats, relu, mean (2x row unroll)
// ---------------------------------------------------------------------------
__global__ __launch_bounds__(128) void pool_mean_kernel(const unsigned short* __restrict__ h,
                                                        const int* __restrict__ gstart,
                                                        const float* __restrict__ stats,
                                                        const float* __restrict__ gamma,
                                                        const float* __restrict__ beta,
                                                        float* __restrict__ out) {
    int g = blockIdx.x;
    int col = threadIdx.x;
    float mu = stats[col] * INV_N;
    float var = stats[128 + col] * INV_N - mu * mu;
    float rs = rsqrtf(var + BN_EPS);
    float c = gamma[col] * rs;
    float b = beta[col] - mu * c;
    int beg = gstart[g];
    int end = gstart[g + 1];
    float s = 0.f;
    int i = beg;
    for (; i + 1 < end; i += 2) {
        float v0 = b2f(h[(size_t)i * 128 + col]);
        float v1 = b2f(h[(size_t)(i + 1) * 128 + col]);
        s += fmaxf(v0 * c + b, 0.f) + fmaxf(v1 * c + b, 0.f);
    }
    if (i < end)
        s += fmaxf(b2f(h[(size_t)i * 128 + col]) * c + b, 0.f);
    float cnt = fmaxf((float)(end - beg), 1.0f);
    out[(size_t)g * 128 + col] = s / cnt;
}

// ---------------------------------------------------------------------------
extern "C" void kernel_launch(void* const* d_in, const int* in_sizes, int n_in,
                              void* d_out, int out_size, void* d_ws, size_t ws_size,
                              hipStream_t stream) {
    const float* x    = (const float*)d_in[0];
    const int*   ei   = (const int*)d_in[1];
    const int*   src  = ei;
    const int*   dst  = ei + N_EDGES;
    const int*   batch = (const int*)d_in[2];
    const float* gw1  = (const float*)d_in[3];
    const float* gb1  = (const float*)d_in[4];
    const float* gw2  = (const float*)d_in[5];
    const float* gb2  = (const float*)d_in[6];
    const float* swl  = (const float*)d_in[7];
    const float* sbl  = (const float*)d_in[8];
    const float* swr  = (const float*)d_in[9];
    const float* bng  = (const float*)d_in[10];
    const float* bnb  = (const float*)d_in[11];
    float* out = (float*)d_out;

    // workspace layout (float units; bf16 buffers 16B-aligned)
    float* ws = (float*)d_ws;
    unsigned short* x16    = (unsigned short*)(ws + 0);
    unsigned short* agg16  = (unsigned short*)(ws + 3200000);
    unsigned short* hact16 = (unsigned short*)(ws + 6400000);
    unsigned short* hpre16 = (unsigned short*)(ws + 9600000);
    unsigned short* wt     = (unsigned short*)(ws + 12800000);  // 6*16384 u16
    float*          inv_deg= ws + 12850000;                     // 50000
    int*            row_beg= (int*)(ws + 12900000);             // 50000
    int*            cursor = (int*)(ws + 12950000);             // 50000 | total | stats(768)
    int*            total  = cursor + 50000;
    float*          stats  = (float*)(cursor + 50001);          // 3*256
    int*            csr_src= (int*)(ws + 13100000);             // 600000
    int*            gstart = (int*)(ws + 13700000);             // 513

    const int aggr_blocks = (N_NODES * 16 + 255) / 256;         // 3125
    const int ntiles32 = (N_NODES + 31) / 32;                   // 1563
    const int ntiles16 = (N_NODES + 15) / 16;                   // 3125
    const int ggrid = 512;

    // ---- init: cursor + total + stats in one memset ----
    hipMemsetAsync(cursor, 0, (50001 + 768) * sizeof(int), stream);

    // ---- prep: x->bf16, weights->bf16^T, degree count ----
    prep_kernel<<<CONVX_BLOCKS + WCONV_BLOCKS + DEG_BLOCKS, 256, 0, stream>>>(
        x, gw1, gw2, swl, swr, dst, x16, wt, cursor);

    // ---- CSR ----
    alloc_kernel<<<ALLOC_BLOCKS + 3, 256, 0, stream>>>(cursor, row_beg, inv_deg, total, batch, gstart);
    csr_fill_kernel<<<(N_EDGES + 255) / 256, 256, 0, stream>>>(src, dst, cursor, csr_src, N_EDGES);

    // ---- GIN ----
    aggregate_kernel<false, false, false><<<aggr_blocks, 256, 0, stream>>>(
        x16, row_beg, cursor, csr_src, nullptr, nullptr, nullptr, nullptr, agg16, nullptr, N_NODES);
    gemm_gin_kernel<<<ggrid, 256, 0, stream>>>(
        x16, agg16, wt + 0 * 16384, wt + 1 * 16384, gb1, gb2, stats + 0, hpre16, N_NODES, ntiles32);

    // ---- SAGE 0 ----
    aggregate_kernel<true, true, true><<<aggr_blocks, 256, 0, stream>>>(
        hpre16, row_beg, cursor, csr_src, stats + 0, bng + 0 * HID, bnb + 0 * HID, inv_deg,
        agg16, hact16, N_NODES);
    gemm_dual_kernel<<<ggrid, 256, 0, stream>>>(
        agg16, hact16, wt + 2 * 16384, wt + 3 * 16384, sbl + 0 * HID, stats + 256, hpre16, N_NODES, ntiles16);

    // ---- SAGE 1 ----
    aggregate_kernel<true, true, true><<<aggr_blocks, 256, 0, stream>>>(
        hpre16, row_beg, cursor, csr_src, stats + 256, bng + 1 * HID, bnb + 1 * HID, inv_deg,
        agg16, hact16, N_NODES);
    gemm_dual_kernel<<<ggrid, 256, 0, stream>>>(
        agg16, hact16, wt + 4 * 16384, wt + 5 * 16384, sbl + 1 * HID, stats + 512, hpre16, N_NODES, ntiles16);

    // ---- pool (BN2 affine folded) ----
    pool_mean_kernel<<<N_GRAPHS, 128, 0, stream>>>(
        hpre16, gstart, stats + 512, bng + 2 * HID, bnb + 2 * HID, out);
}